// Round 1
// baseline (1690.793 us; speedup 1.0000x reference)
//
#include <hip/hip_runtime.h>
#include <hip/hip_bf16.h>
#include <math.h>

#define DF 128
#define HID 256
#define NG 256

// ---------------- CSR build ----------------
__global__ void k_hist(const int* __restrict__ dst, int* __restrict__ cnt, int E){
  int e = blockIdx.x*256 + threadIdx.x;
  if (e < E) atomicAdd(&cnt[dst[e]], 1);
}

// tile = 1024 elements (256 thr x 4), exclusive scan within tile + block sums
__global__ void k_scan_tile(const int* __restrict__ cnt, int* __restrict__ offs,
                            int* __restrict__ bsums, int n){
  __shared__ int sh[256];
  int t = threadIdx.x;
  int base = blockIdx.x*1024 + t*4;
  int v0=0,v1=0,v2=0,v3=0;
  if (base+0 < n) v0 = cnt[base+0];
  if (base+1 < n) v1 = cnt[base+1];
  if (base+2 < n) v2 = cnt[base+2];
  if (base+3 < n) v3 = cnt[base+3];
  int s = v0+v1+v2+v3;
  sh[t] = s; __syncthreads();
  for (int o=1;o<256;o<<=1){
    int x = (t>=o)? sh[t-o] : 0;
    __syncthreads();
    sh[t] += x;
    __syncthreads();
  }
  int run = sh[t] - s;  // exclusive prefix of this thread
  if (base+0 < n) offs[base+0] = run;
  run += v0;
  if (base+1 < n) offs[base+1] = run;
  run += v1;
  if (base+2 < n) offs[base+2] = run;
  run += v2;
  if (base+3 < n) offs[base+3] = run;
  if (t==255) bsums[blockIdx.x] = sh[255];
}

__global__ void k_scan_bsums(const int* __restrict__ bsums, int* __restrict__ boff, int nb){
  __shared__ int sh[1024];
  int t = threadIdx.x;
  int s = (t<nb)? bsums[t] : 0;
  sh[t]=s; __syncthreads();
  for (int o=1;o<1024;o<<=1){
    int x = (t>=o)? sh[t-o]:0;
    __syncthreads();
    sh[t]+=x;
    __syncthreads();
  }
  if (t<nb) boff[t] = sh[t]-s;
}

__global__ void k_scan_add(int* __restrict__ offs, int* __restrict__ cursor,
                           const int* __restrict__ boff, int n, int E){
  int i = blockIdx.x*256+threadIdx.x;
  if (i<n){
    int v = offs[i] + boff[i>>10];
    offs[i]=v; cursor[i]=v;
  }
  if (i==0 && blockIdx.x==0) offs[n]=E;
}

__global__ void k_fill(const int* __restrict__ src, const int* __restrict__ dst,
                       int* __restrict__ cursor, int* __restrict__ csr_src, int E){
  int e = blockIdx.x*256+threadIdx.x;
  if (e<E){
    int pos = atomicAdd(&cursor[dst[e]],1);
    csr_src[pos]=src[e];
  }
}

// ---------------- embedding gather ----------------
__global__ void k_embed(const int* __restrict__ feat, const float* __restrict__ emb,
                        float* __restrict__ h, int N){
  int idx = blockIdx.x*256+threadIdx.x; // float4 index
  int total = N*(DF/4);
  if (idx<total){
    int i = idx/(DF/4), c = idx%(DF/4);
    ((float4*)h)[idx] = ((const float4*)emb)[(size_t)feat[i]*(DF/4)+c];
  }
}

// ---------------- fused SAGE layer: gather-mean + dual GEMM + bias + relu ----------------
// block = 256 threads, 32 nodes/block. LDS 32KB.
__global__ __launch_bounds__(256,2)
void k_sage(const float* __restrict__ h_in,
            const int* __restrict__ offs, const int* __restrict__ csr,
            const float* __restrict__ ws, const float* __restrict__ wn,
            const float* __restrict__ bias, float* __restrict__ h_out, int N){
  __shared__ float s_self[32][DF];
  __shared__ float s_ngh[32][DF];
  const int t = threadIdx.x;
  const int node0 = blockIdx.x*32;

  // stage self rows (coalesced float4)
  for (int idx = t; idx < 32*(DF/4); idx += 256){
    int nn = idx/(DF/4), c = idx%(DF/4);
    int node = node0+nn;
    float4 v = make_float4(0.f,0.f,0.f,0.f);
    if (node<N) v = ((const float4*)h_in)[(size_t)node*(DF/4)+c];
    ((float4*)&s_self[nn][0])[c]=v;
  }

  // neighbor mean-aggregate: two 128-thread halves, each owns column d of its node
  {
    int half = t>>7, d = t&127;
    for (int nn=half; nn<32; nn+=2){
      int node = node0+nn;
      float acc=0.f;
      if (node<N){
        int e0=offs[node], e1=offs[node+1];
        for (int e=e0;e<e1;++e){
          int sidx = csr[e];
          acc += h_in[(size_t)sidx*DF + d];
        }
        acc /= fmaxf((float)(e1-e0),1.0f);
      }
      s_ngh[nn][d]=acc;
    }
  }
  __syncthreads();

  // register-tiled dual GEMM: thread owns cols d0..d0+3, rows rg+8r (r=0..3)
  const int d0 = (t&31)*4;
  const int rg = t>>5;
  float acc[4][4];
  #pragma unroll
  for (int r=0;r<4;r++)
    #pragma unroll
    for (int c=0;c<4;c++) acc[r][c]=0.f;

  for (int kk=0; kk<DF; kk+=4){
    float wsv[4][4], wnv[4][4];
    #pragma unroll
    for (int j=0;j<4;j++){
      *(float4*)wsv[j] = *(const float4*)&ws[(kk+j)*DF + d0];
      *(float4*)wnv[j] = *(const float4*)&wn[(kk+j)*DF + d0];
    }
    #pragma unroll
    for (int r=0;r<4;r++){
      int nn = rg + 8*r;
      float av[4], gv[4];
      *(float4*)av = *(const float4*)&s_self[nn][kk];
      *(float4*)gv = *(const float4*)&s_ngh[nn][kk];
      #pragma unroll
      for (int j=0;j<4;j++)
        #pragma unroll
        for (int c=0;c<4;c++)
          acc[r][c] += av[j]*wsv[j][c] + gv[j]*wnv[j][c];
    }
  }

  #pragma unroll
  for (int r=0;r<4;r++){
    int nn = rg+8*r; int node=node0+nn;
    if (node<N){
      float4 o;
      float* op=(float*)&o;
      #pragma unroll
      for (int c=0;c<4;c++) op[c] = fmaxf(acc[r][c]+bias[d0+c], 0.f);
      *(float4*)&h_out[(size_t)node*DF+d0] = o;
    }
  }
}

// ---------------- graph mean pool (graph_id sorted) ----------------
__global__ void k_pool(const float* __restrict__ h, const int* __restrict__ gid,
                       float* __restrict__ gsum, float* __restrict__ gcnt, int N){
  int d = threadIdx.x; // 128
  int i0 = blockIdx.x*512;
  if (i0>=N) return;
  int i1 = i0+512; if (i1>N) i1=N;
  int cur = gid[i0];
  float run=0.f, crun=0.f;
  for (int i=i0;i<i1;++i){
    int g = gid[i];
    if (g!=cur){
      atomicAdd(&gsum[cur*DF+d], run);
      if (d==0) atomicAdd(&gcnt[cur], crun);
      run=0.f; crun=0.f; cur=g;
    }
    run += h[(size_t)i*DF+d];
    crun += 1.f;
  }
  atomicAdd(&gsum[cur*DF+d], run);
  if (d==0) atomicAdd(&gcnt[cur], crun);
}

// ---------------- MLP head ----------------
__global__ void k_mlp1(const float* __restrict__ gsum, const float* __restrict__ gcnt,
                       const float* __restrict__ w, const float* __restrict__ b,
                       float* __restrict__ out){ // [NG][HID] = hidden
  __shared__ float sh[DF];
  int g = blockIdx.x, t = threadIdx.x;
  if (t<DF) sh[t] = gsum[g*DF+t] / fmaxf(gcnt[g],1.0f);
  __syncthreads();
  float acc = b[t];
  for (int k=0;k<DF;++k) acc += sh[k]*w[k*HID+t];
  out[g*HID+t] = fmaxf(acc,0.f);
}

__global__ void k_mlp(const float* __restrict__ in, const float* __restrict__ w,
                      const float* __restrict__ b, float* __restrict__ out, int relu){
  __shared__ float sh[HID];
  int i = blockIdx.x, t = threadIdx.x;
  sh[t] = in[i*HID+t];
  __syncthreads();
  float acc = b[t];
  for (int k=0;k<HID;++k) acc += sh[k]*w[k*HID+t];
  out[i*HID+t] = relu? fmaxf(acc,0.f) : acc;
}

__global__ void k_pred(const float* __restrict__ h4, const float* __restrict__ pw,
                       const float* __restrict__ pb, float* __restrict__ out){
  int i = threadIdx.x;
  if (i>=NG) return;
  float y0=pb[0], y1=pb[1];
  for (int k=0;k<HID;++k){
    float a = h4[i*HID+k];
    y0 += a*pw[k*2+0];
    y1 += a*pw[k*2+1];
  }
  float m = fmaxf(y0,y1);
  float l = m + logf(expf(y0-m)+expf(y1-m));
  out[i*2+0]=y0-l;
  out[i*2+1]=y1-l;
}

extern "C" void kernel_launch(void* const* d_in, const int* in_sizes, int n_in,
                              void* d_out, int out_size, void* d_ws, size_t ws_size,
                              hipStream_t stream){
  const int* feat = (const int*)d_in[0];
  const int* src  = (const int*)d_in[1];
  const int* dst  = (const int*)d_in[2];
  const int* gid  = (const int*)d_in[3];
  const float* emb = (const float*)d_in[4];
  const float* ws0 = (const float*)d_in[5];
  const float* wn0 = (const float*)d_in[6];
  const float* b0  = (const float*)d_in[7];
  const float* ws1 = (const float*)d_in[8];
  const float* wn1 = (const float*)d_in[9];
  const float* b1  = (const float*)d_in[10];
  const float* e1w = (const float*)d_in[11];
  const float* e1b = (const float*)d_in[12];
  const float* e2w = (const float*)d_in[13];
  const float* e2b = (const float*)d_in[14];
  const float* e3w = (const float*)d_in[15];
  const float* e3b = (const float*)d_in[16];
  const float* e4w = (const float*)d_in[17];
  const float* e4b = (const float*)d_in[18];
  const float* pw  = (const float*)d_in[19];
  const float* pb  = (const float*)d_in[20];
  const int N = in_sizes[0];
  const int E = in_sizes[1];

  char* basep = (char*)d_ws;
  size_t off=0;
  auto alloc=[&](size_t bytes)->void*{
    void* p = basep+off; off=(off+bytes+255)&~(size_t)255; return p;
  };
  float* hA    = (float*)alloc((size_t)N*DF*4);
  float* hB    = (float*)alloc((size_t)N*DF*4);
  int*   cnt   = (int*)  alloc((size_t)N*4);
  int*   offs  = (int*)  alloc((size_t)(N+1)*4);
  int*   cursor= (int*)  alloc((size_t)N*4);
  int*   bsums = (int*)  alloc(4096);
  int*   boff  = (int*)  alloc(4096);
  int*   csr   = (int*)  alloc((size_t)E*4);
  float* gsum  = (float*)alloc((size_t)NG*DF*4);
  float* gcnt  = (float*)alloc((size_t)NG*4);
  float* t1    = (float*)alloc((size_t)NG*HID*4);
  float* t2    = (float*)alloc((size_t)NG*HID*4);
  float* out    = (float*)d_out;
  float* hidden = out + NG*2;   // output 1 region, also MLP intermediate

  hipMemsetAsync(cnt, 0, (size_t)N*4, stream);
  hipMemsetAsync(gsum, 0, (size_t)NG*DF*4, stream);
  hipMemsetAsync(gcnt, 0, (size_t)NG*4, stream);

  k_hist<<<(E+255)/256,256,0,stream>>>(dst,cnt,E);
  int nb = (N+1023)/1024;
  k_scan_tile<<<nb,256,0,stream>>>(cnt,offs,bsums,N);
  k_scan_bsums<<<1,1024,0,stream>>>(bsums,boff,nb);
  k_scan_add<<<(N+255)/256,256,0,stream>>>(offs,cursor,boff,N,E);
  k_fill<<<(E+255)/256,256,0,stream>>>(src,dst,cursor,csr,E);

  k_embed<<<(N*(DF/4)+255)/256,256,0,stream>>>(feat,emb,hA,N);
  k_sage<<<(N+31)/32,256,0,stream>>>(hA,offs,csr,ws0,wn0,b0,hB,N);
  k_sage<<<(N+31)/32,256,0,stream>>>(hB,offs,csr,ws1,wn1,b1,hA,N);

  k_pool<<<(N+511)/512,128,0,stream>>>(hA,gid,gsum,gcnt,N);
  k_mlp1<<<NG,HID,0,stream>>>(gsum,gcnt,e1w,e1b,hidden);
  k_mlp<<<NG,HID,0,stream>>>(hidden,e2w,e2b,t1,1);
  k_mlp<<<NG,HID,0,stream>>>(t1,e3w,e3b,t2,1);
  k_mlp<<<NG,HID,0,stream>>>(t2,e4w,e4b,t1,1);
  k_pred<<<1,256,0,stream>>>(t1,pw,pb,out);
}

// Round 2
// 812.588 us; speedup vs baseline: 2.0808x; 2.0808x over previous
//
#include <hip/hip_runtime.h>
#include <hip/hip_bf16.h>
#include <math.h>

#define DF 128
#define HID 256
#define NG 256

// ---------------- CSR build ----------------
__global__ void k_hist(const int* __restrict__ dst, int* __restrict__ cnt, int E){
  int e = blockIdx.x*256 + threadIdx.x;
  if (e < E) atomicAdd(&cnt[dst[e]], 1);
}

// tile = 1024 elements (256 thr x 4), exclusive scan within tile + block sums
__global__ void k_scan_tile(const int* __restrict__ cnt, int* __restrict__ offs,
                            int* __restrict__ bsums, int n){
  __shared__ int sh[256];
  int t = threadIdx.x;
  int base = blockIdx.x*1024 + t*4;
  int v0=0,v1=0,v2=0,v3=0;
  if (base+0 < n) v0 = cnt[base+0];
  if (base+1 < n) v1 = cnt[base+1];
  if (base+2 < n) v2 = cnt[base+2];
  if (base+3 < n) v3 = cnt[base+3];
  int s = v0+v1+v2+v3;
  sh[t] = s; __syncthreads();
  for (int o=1;o<256;o<<=1){
    int x = (t>=o)? sh[t-o] : 0;
    __syncthreads();
    sh[t] += x;
    __syncthreads();
  }
  int run = sh[t] - s;  // exclusive prefix of this thread
  if (base+0 < n) offs[base+0] = run;
  run += v0;
  if (base+1 < n) offs[base+1] = run;
  run += v1;
  if (base+2 < n) offs[base+2] = run;
  run += v2;
  if (base+3 < n) offs[base+3] = run;
  if (t==255) bsums[blockIdx.x] = sh[255];
}

__global__ void k_scan_bsums(const int* __restrict__ bsums, int* __restrict__ boff, int nb){
  __shared__ int sh[1024];
  int t = threadIdx.x;
  int s = (t<nb)? bsums[t] : 0;
  sh[t]=s; __syncthreads();
  for (int o=1;o<1024;o<<=1){
    int x = (t>=o)? sh[t-o]:0;
    __syncthreads();
    sh[t]+=x;
    __syncthreads();
  }
  if (t<nb) boff[t] = sh[t]-s;
}

__global__ void k_scan_add(int* __restrict__ offs, int* __restrict__ cursor,
                           const int* __restrict__ boff, int n, int E){
  int i = blockIdx.x*256+threadIdx.x;
  if (i<n){
    int v = offs[i] + boff[i>>10];
    offs[i]=v; cursor[i]=v;
  }
  if (i==0 && blockIdx.x==0) offs[n]=E;
}

__global__ void k_fill(const int* __restrict__ src, const int* __restrict__ dst,
                       int* __restrict__ cursor, int* __restrict__ csr_src, int E){
  int e = blockIdx.x*256+threadIdx.x;
  if (e<E){
    int pos = atomicAdd(&cursor[dst[e]],1);
    csr_src[pos]=src[e];
  }
}

// ---------------- embedding gather ----------------
__global__ void k_embed(const int* __restrict__ feat, const float* __restrict__ emb,
                        float* __restrict__ h, int N){
  int idx = blockIdx.x*256+threadIdx.x; // float4 index
  int total = N*(DF/4);
  if (idx<total){
    int i = idx/(DF/4), c = idx%(DF/4);
    ((float4*)h)[idx] = ((const float4*)emb)[(size_t)feat[i]*(DF/4)+c];
  }
}

// ---------------- fused SAGE layer: gather-mean + dual GEMM + bias + relu ----------------
// block = 256 threads, 32 nodes/block. LDS 32KB.
// Aggregation: thread t owns node (t>>3) and 16-col chunk (t&7) -> all 32
// nodes aggregate concurrently, 4 independent float4 loads in flight per
// thread, csr index software-prefetched.
__global__ __launch_bounds__(256,2)
void k_sage(const float* __restrict__ h_in,
            const int* __restrict__ offs, const int* __restrict__ csr,
            const float* __restrict__ ws, const float* __restrict__ wn,
            const float* __restrict__ bias, float* __restrict__ h_out, int N){
  __shared__ float s_self[32][DF];
  __shared__ float s_ngh[32][DF];
  const int t = threadIdx.x;
  const int node0 = blockIdx.x*32;

  // stage self rows (coalesced float4)
  for (int idx = t; idx < 32*(DF/4); idx += 256){
    int nn = idx/(DF/4), c = idx%(DF/4);
    int node = node0+nn;
    float4 v = make_float4(0.f,0.f,0.f,0.f);
    if (node<N) v = ((const float4*)h_in)[(size_t)node*(DF/4)+c];
    ((float4*)&s_self[nn][0])[c]=v;
  }

  // neighbor mean-aggregate, fully node-parallel
  {
    const int nn = t>>3;        // node 0..31
    const int c  = t&7;         // 16-col chunk
    const int node = node0+nn;
    float a0x=0,a0y=0,a0z=0,a0w=0, a1x=0,a1y=0,a1z=0,a1w=0;
    float a2x=0,a2y=0,a2z=0,a2w=0, a3x=0,a3y=0,a3z=0,a3w=0;
    if (node<N){
      int e0=offs[node], e1=offs[node+1];
      if (e1>e0){
        const float4* base4 = (const float4*)h_in;
        int sidx = csr[e0];
        for (int e=e0+1; e<=e1; ++e){
          int nxt = (e<e1)? csr[e] : 0;
          const float4* p = base4 + (size_t)sidx*(DF/4) + c*4;
          float4 v0=p[0], v1=p[1], v2=p[2], v3=p[3];
          a0x+=v0.x; a0y+=v0.y; a0z+=v0.z; a0w+=v0.w;
          a1x+=v1.x; a1y+=v1.y; a1z+=v1.z; a1w+=v1.w;
          a2x+=v2.x; a2y+=v2.y; a2z+=v2.z; a2w+=v2.w;
          a3x+=v3.x; a3y+=v3.y; a3z+=v3.z; a3w+=v3.w;
          sidx = nxt;
        }
        float inv = 1.0f/(float)(e1-e0);
        a0x*=inv;a0y*=inv;a0z*=inv;a0w*=inv; a1x*=inv;a1y*=inv;a1z*=inv;a1w*=inv;
        a2x*=inv;a2y*=inv;a2z*=inv;a2w*=inv; a3x*=inv;a3y*=inv;a3z*=inv;a3w*=inv;
      }
    }
    float4* op = (float4*)&s_ngh[nn][c*16];
    op[0]=make_float4(a0x,a0y,a0z,a0w);
    op[1]=make_float4(a1x,a1y,a1z,a1w);
    op[2]=make_float4(a2x,a2y,a2z,a2w);
    op[3]=make_float4(a3x,a3y,a3z,a3w);
  }
  __syncthreads();

  // register-tiled dual GEMM: thread owns cols d0..d0+3, rows rg+8r (r=0..3)
  const int d0 = (t&31)*4;
  const int rg = t>>5;
  float acc[4][4];
  #pragma unroll
  for (int r=0;r<4;r++)
    #pragma unroll
    for (int c=0;c<4;c++) acc[r][c]=0.f;

  for (int kk=0; kk<DF; kk+=4){
    float wsv[4][4], wnv[4][4];
    #pragma unroll
    for (int j=0;j<4;j++){
      *(float4*)wsv[j] = *(const float4*)&ws[(kk+j)*DF + d0];
      *(float4*)wnv[j] = *(const float4*)&wn[(kk+j)*DF + d0];
    }
    #pragma unroll
    for (int r=0;r<4;r++){
      int nn = rg + 8*r;
      float av[4], gv[4];
      *(float4*)av = *(const float4*)&s_self[nn][kk];
      *(float4*)gv = *(const float4*)&s_ngh[nn][kk];
      #pragma unroll
      for (int j=0;j<4;j++)
        #pragma unroll
        for (int c=0;c<4;c++)
          acc[r][c] += av[j]*wsv[j][c] + gv[j]*wnv[j][c];
    }
  }

  #pragma unroll
  for (int r=0;r<4;r++){
    int nn = rg+8*r; int node=node0+nn;
    if (node<N){
      float4 o;
      float* op=(float*)&o;
      #pragma unroll
      for (int c=0;c<4;c++) op[c] = fmaxf(acc[r][c]+bias[d0+c], 0.f);
      *(float4*)&h_out[(size_t)node*DF+d0] = o;
    }
  }
}

// ---------------- graph mean pool (graph_id sorted) ----------------
__global__ void k_pool(const float* __restrict__ h, const int* __restrict__ gid,
                       float* __restrict__ gsum, float* __restrict__ gcnt, int N){
  int d = threadIdx.x; // 128
  int i0 = blockIdx.x*512;
  if (i0>=N) return;
  int i1 = i0+512; if (i1>N) i1=N;
  int cur = gid[i0];
  float run=0.f, crun=0.f;
  for (int i=i0;i<i1;++i){
    int g = gid[i];
    if (g!=cur){
      atomicAdd(&gsum[cur*DF+d], run);
      if (d==0) atomicAdd(&gcnt[cur], crun);
      run=0.f; crun=0.f; cur=g;
    }
    run += h[(size_t)i*DF+d];
    crun += 1.f;
  }
  atomicAdd(&gsum[cur*DF+d], run);
  if (d==0) atomicAdd(&gcnt[cur], crun);
}

// ---------------- MLP head ----------------
__global__ void k_mlp1(const float* __restrict__ gsum, const float* __restrict__ gcnt,
                       const float* __restrict__ w, const float* __restrict__ b,
                       float* __restrict__ out){ // [NG][HID] = hidden
  __shared__ float sh[DF];
  int g = blockIdx.x, t = threadIdx.x;
  if (t<DF) sh[t] = gsum[g*DF+t] / fmaxf(gcnt[g],1.0f);
  __syncthreads();
  float acc = b[t];
  for (int k=0;k<DF;++k) acc += sh[k]*w[k*HID+t];
  out[g*HID+t] = fmaxf(acc,0.f);
}

__global__ void k_mlp(const float* __restrict__ in, const float* __restrict__ w,
                      const float* __restrict__ b, float* __restrict__ out, int relu){
  __shared__ float sh[HID];
  int i = blockIdx.x, t = threadIdx.x;
  sh[t] = in[i*HID+t];
  __syncthreads();
  float acc = b[t];
  for (int k=0;k<HID;++k) acc += sh[k]*w[k*HID+t];
  out[i*HID+t] = relu? fmaxf(acc,0.f) : acc;
}

__global__ void k_pred(const float* __restrict__ h4, const float* __restrict__ pw,
                       const float* __restrict__ pb, float* __restrict__ out){
  int i = threadIdx.x;
  if (i>=NG) return;
  float y0=pb[0], y1=pb[1];
  for (int k=0;k<HID;++k){
    float a = h4[i*HID+k];
    y0 += a*pw[k*2+0];
    y1 += a*pw[k*2+1];
  }
  float m = fmaxf(y0,y1);
  float l = m + logf(expf(y0-m)+expf(y1-m));
  out[i*2+0]=y0-l;
  out[i*2+1]=y1-l;
}

extern "C" void kernel_launch(void* const* d_in, const int* in_sizes, int n_in,
                              void* d_out, int out_size, void* d_ws, size_t ws_size,
                              hipStream_t stream){
  const int* feat = (const int*)d_in[0];
  const int* src  = (const int*)d_in[1];
  const int* dst  = (const int*)d_in[2];
  const int* gid  = (const int*)d_in[3];
  const float* emb = (const float*)d_in[4];
  const float* ws0 = (const float*)d_in[5];
  const float* wn0 = (const float*)d_in[6];
  const float* b0  = (const float*)d_in[7];
  const float* ws1 = (const float*)d_in[8];
  const float* wn1 = (const float*)d_in[9];
  const float* b1  = (const float*)d_in[10];
  const float* e1w = (const float*)d_in[11];
  const float* e1b = (const float*)d_in[12];
  const float* e2w = (const float*)d_in[13];
  const float* e2b = (const float*)d_in[14];
  const float* e3w = (const float*)d_in[15];
  const float* e3b = (const float*)d_in[16];
  const float* e4w = (const float*)d_in[17];
  const float* e4b = (const float*)d_in[18];
  const float* pw  = (const float*)d_in[19];
  const float* pb  = (const float*)d_in[20];
  const int N = in_sizes[0];
  const int E = in_sizes[1];

  char* basep = (char*)d_ws;
  size_t off=0;
  auto alloc=[&](size_t bytes)->void*{
    void* p = basep+off; off=(off+bytes+255)&~(size_t)255; return p;
  };
  float* hA    = (float*)alloc((size_t)N*DF*4);
  float* hB    = (float*)alloc((size_t)N*DF*4);
  int*   cnt   = (int*)  alloc((size_t)N*4);
  int*   offs  = (int*)  alloc((size_t)(N+1)*4);
  int*   cursor= (int*)  alloc((size_t)N*4);
  int*   bsums = (int*)  alloc(4096);
  int*   boff  = (int*)  alloc(4096);
  int*   csr   = (int*)  alloc((size_t)E*4);
  float* gsum  = (float*)alloc((size_t)NG*DF*4);
  float* gcnt  = (float*)alloc((size_t)NG*4);
  float* t1    = (float*)alloc((size_t)NG*HID*4);
  float* t2    = (float*)alloc((size_t)NG*HID*4);
  float* out    = (float*)d_out;
  float* hidden = out + NG*2;   // output 1 region, also MLP intermediate

  hipMemsetAsync(cnt, 0, (size_t)N*4, stream);
  hipMemsetAsync(gsum, 0, (size_t)NG*DF*4, stream);
  hipMemsetAsync(gcnt, 0, (size_t)NG*4, stream);

  k_hist<<<(E+255)/256,256,0,stream>>>(dst,cnt,E);
  int nb = (N+1023)/1024;
  k_scan_tile<<<nb,256,0,stream>>>(cnt,offs,bsums,N);
  k_scan_bsums<<<1,1024,0,stream>>>(bsums,boff,nb);
  k_scan_add<<<(N+255)/256,256,0,stream>>>(offs,cursor,boff,N,E);
  k_fill<<<(E+255)/256,256,0,stream>>>(src,dst,cursor,csr,E);

  k_embed<<<(N*(DF/4)+255)/256,256,0,stream>>>(feat,emb,hA,N);
  k_sage<<<(N+31)/32,256,0,stream>>>(hA,offs,csr,ws0,wn0,b0,hB,N);
  k_sage<<<(N+31)/32,256,0,stream>>>(hB,offs,csr,ws1,wn1,b1,hA,N);

  k_pool<<<(N+511)/512,128,0,stream>>>(hA,gid,gsum,gcnt,N);
  k_mlp1<<<NG,HID,0,stream>>>(gsum,gcnt,e1w,e1b,hidden);
  k_mlp<<<NG,HID,0,stream>>>(hidden,e2w,e2b,t1,1);
  k_mlp<<<NG,HID,0,stream>>>(t1,e3w,e3b,t2,1);
  k_mlp<<<NG,HID,0,stream>>>(t2,e4w,e4b,t1,1);
  k_pred<<<1,256,0,stream>>>(t1,pw,pb,out);
}

// Round 3
// 642.870 us; speedup vs baseline: 2.6301x; 1.2640x over previous
//
#include <hip/hip_runtime.h>
#include <hip/hip_bf16.h>
#include <math.h>

#define DF 128
#define HID 256
#define NG 256

__device__ __forceinline__ float bf_lo(unsigned u){
  union{unsigned i; float f;} c; c.i = u<<16; return c.f;
}
__device__ __forceinline__ float bf_hi(unsigned u){
  union{unsigned i; float f;} c; c.i = u & 0xffff0000u; return c.f;
}
__device__ __forceinline__ unsigned pack2bf(float lo, float hi){
  unsigned a = __bfloat16_as_ushort(__float2bfloat16(lo));
  unsigned b = __bfloat16_as_ushort(__float2bfloat16(hi));
  return a | (b<<16);
}

// ---------------- CSR build ----------------
__global__ void k_hist(const int* __restrict__ dst, int* __restrict__ cnt, int E){
  int e = blockIdx.x*256 + threadIdx.x;
  if (e < E) atomicAdd(&cnt[dst[e]], 1);
}

__global__ void k_scan_tile(const int* __restrict__ cnt, int* __restrict__ offs,
                            int* __restrict__ bsums, int n){
  __shared__ int sh[256];
  int t = threadIdx.x;
  int base = blockIdx.x*1024 + t*4;
  int v0=0,v1=0,v2=0,v3=0;
  if (base+0 < n) v0 = cnt[base+0];
  if (base+1 < n) v1 = cnt[base+1];
  if (base+2 < n) v2 = cnt[base+2];
  if (base+3 < n) v3 = cnt[base+3];
  int s = v0+v1+v2+v3;
  sh[t] = s; __syncthreads();
  for (int o=1;o<256;o<<=1){
    int x = (t>=o)? sh[t-o] : 0;
    __syncthreads();
    sh[t] += x;
    __syncthreads();
  }
  int run = sh[t] - s;
  if (base+0 < n) offs[base+0] = run;
  run += v0;
  if (base+1 < n) offs[base+1] = run;
  run += v1;
  if (base+2 < n) offs[base+2] = run;
  run += v2;
  if (base+3 < n) offs[base+3] = run;
  if (t==255) bsums[blockIdx.x] = sh[255];
}

__global__ void k_scan_bsums(const int* __restrict__ bsums, int* __restrict__ boff, int nb){
  __shared__ int sh[1024];
  int t = threadIdx.x;
  int s = (t<nb)? bsums[t] : 0;
  sh[t]=s; __syncthreads();
  for (int o=1;o<1024;o<<=1){
    int x = (t>=o)? sh[t-o]:0;
    __syncthreads();
    sh[t]+=x;
    __syncthreads();
  }
  if (t<nb) boff[t] = sh[t]-s;
}

__global__ void k_scan_add(int* __restrict__ offs, int* __restrict__ cursor,
                           const int* __restrict__ boff, int n, int E){
  int i = blockIdx.x*256+threadIdx.x;
  if (i<n){
    int v = offs[i] + boff[i>>10];
    offs[i]=v; cursor[i]=v;
  }
  if (i==0 && blockIdx.x==0) offs[n]=E;
}

__global__ void k_fill(const int* __restrict__ src, const int* __restrict__ dst,
                       int* __restrict__ cursor, int* __restrict__ csr_src, int E){
  int e = blockIdx.x*256+threadIdx.x;
  if (e<E){
    int pos = atomicAdd(&cursor[dst[e]],1);
    csr_src[pos]=src[e];
  }
}

// ---------------- embedding gather -> bf16 h ----------------
__global__ void k_embed(const int* __restrict__ feat, const float* __restrict__ emb,
                        unsigned* __restrict__ h4, int N){
  // each thread: one uint4 = 8 bf16 elements
  int idx = blockIdx.x*256+threadIdx.x;
  int total = N*(DF/8);
  if (idx<total){
    int i = idx/(DF/8), c = idx%(DF/8);
    const float4* e4 = (const float4*)emb;
    size_t rb = (size_t)feat[i]*(DF/4);
    float4 v0 = e4[rb + c*2], v1 = e4[rb + c*2+1];
    uint4 o;
    o.x = pack2bf(v0.x,v0.y); o.y = pack2bf(v0.z,v0.w);
    o.z = pack2bf(v1.x,v1.y); o.w = pack2bf(v1.z,v1.w);
    ((uint4*)h4)[idx] = o;
  }
}

// ---------------- fused SAGE layer (bf16 h) ----------------
// block = 256 threads, 32 nodes/block.
// gather: thread t owns node (t>>3), 16-col chunk (t&7); rows are bf16 (256B),
// lane reads 2x uint4 (32B) per edge, accumulates f32.
__global__ __launch_bounds__(256,4)
void k_sage(const unsigned short* __restrict__ h_in,
            const int* __restrict__ offs, const int* __restrict__ csr,
            const float* __restrict__ ws, const float* __restrict__ wn,
            const float* __restrict__ bias, unsigned short* __restrict__ h_out, int N){
  __shared__ float s_self[32][DF];
  __shared__ float s_ngh[32][DF];
  const int t = threadIdx.x;
  const int node0 = blockIdx.x*32;
  const uint4* hin4 = (const uint4*)h_in;   // 16 uint4 per row

  // stage self rows bf16 -> f32 LDS
  for (int idx = t; idx < 32*(DF/8); idx += 256){
    int nn = idx>>4, c = idx&15;            // c: uint4 chunk (8 elems)
    int node = node0+nn;
    uint4 q = make_uint4(0,0,0,0);
    if (node<N) q = hin4[(size_t)node*16 + c];
    float* dp = &s_self[nn][c*8];
    dp[0]=bf_lo(q.x); dp[1]=bf_hi(q.x);
    dp[2]=bf_lo(q.y); dp[3]=bf_hi(q.y);
    dp[4]=bf_lo(q.z); dp[5]=bf_hi(q.z);
    dp[6]=bf_lo(q.w); dp[7]=bf_hi(q.w);
  }

  // neighbor mean-aggregate, node-parallel, f32 accum
  {
    const int nn = t>>3;
    const int c  = t&7;
    const int node = node0+nn;
    float a[16];
    #pragma unroll
    for (int j=0;j<16;j++) a[j]=0.f;
    if (node<N){
      int e0=offs[node], e1=offs[node+1];
      if (e1>e0){
        int sidx = csr[e0];
        for (int e=e0+1; e<=e1; ++e){
          int nxt = (e<e1)? csr[e] : 0;
          const uint4* p = hin4 + (size_t)sidx*16 + c*2;
          uint4 q0 = p[0], q1 = p[1];
          a[0]+=bf_lo(q0.x); a[1]+=bf_hi(q0.x);
          a[2]+=bf_lo(q0.y); a[3]+=bf_hi(q0.y);
          a[4]+=bf_lo(q0.z); a[5]+=bf_hi(q0.z);
          a[6]+=bf_lo(q0.w); a[7]+=bf_hi(q0.w);
          a[8]+=bf_lo(q1.x); a[9]+=bf_hi(q1.x);
          a[10]+=bf_lo(q1.y); a[11]+=bf_hi(q1.y);
          a[12]+=bf_lo(q1.z); a[13]+=bf_hi(q1.z);
          a[14]+=bf_lo(q1.w); a[15]+=bf_hi(q1.w);
          sidx = nxt;
        }
        float inv = 1.0f/(float)(e1-e0);
        #pragma unroll
        for (int j=0;j<16;j++) a[j]*=inv;
      }
    }
    float4* op = (float4*)&s_ngh[nn][c*16];
    op[0]=make_float4(a[0],a[1],a[2],a[3]);
    op[1]=make_float4(a[4],a[5],a[6],a[7]);
    op[2]=make_float4(a[8],a[9],a[10],a[11]);
    op[3]=make_float4(a[12],a[13],a[14],a[15]);
  }
  __syncthreads();

  // register-tiled dual GEMM (f32): thread owns cols d0..d0+3, rows rg+8r
  const int d0 = (t&31)*4;
  const int rg = t>>5;
  float acc[4][4];
  #pragma unroll
  for (int r=0;r<4;r++)
    #pragma unroll
    for (int c=0;c<4;c++) acc[r][c]=0.f;

  for (int kk=0; kk<DF; kk+=4){
    float wsv[4][4], wnv[4][4];
    #pragma unroll
    for (int j=0;j<4;j++){
      *(float4*)wsv[j] = *(const float4*)&ws[(kk+j)*DF + d0];
      *(float4*)wnv[j] = *(const float4*)&wn[(kk+j)*DF + d0];
    }
    #pragma unroll
    for (int r=0;r<4;r++){
      int nn = rg + 8*r;
      float av[4], gv[4];
      *(float4*)av = *(const float4*)&s_self[nn][kk];
      *(float4*)gv = *(const float4*)&s_ngh[nn][kk];
      #pragma unroll
      for (int j=0;j<4;j++)
        #pragma unroll
        for (int c=0;c<4;c++)
          acc[r][c] += av[j]*wsv[j][c] + gv[j]*wnv[j][c];
    }
  }

  #pragma unroll
  for (int r=0;r<4;r++){
    int nn = rg+8*r; int node=node0+nn;
    if (node<N){
      float o0 = fmaxf(acc[r][0]+bias[d0+0], 0.f);
      float o1 = fmaxf(acc[r][1]+bias[d0+1], 0.f);
      float o2 = fmaxf(acc[r][2]+bias[d0+2], 0.f);
      float o3 = fmaxf(acc[r][3]+bias[d0+3], 0.f);
      uint2 o;
      o.x = pack2bf(o0,o1); o.y = pack2bf(o2,o3);
      *(uint2*)&h_out[(size_t)node*DF+d0] = o;
    }
  }
}

// ---------------- graph mean pool (graph_id sorted, bf16 h) ----------------
__global__ void k_pool(const unsigned short* __restrict__ h, const int* __restrict__ gid,
                       float* __restrict__ gsum, float* __restrict__ gcnt, int N){
  int d = threadIdx.x; // 128
  int i0 = blockIdx.x*256;
  if (i0>=N) return;
  int i1 = i0+256; if (i1>N) i1=N;
  int cur = gid[i0];
  float run=0.f, crun=0.f;
  for (int i=i0;i<i1;++i){
    int g = gid[i];
    if (g!=cur){
      atomicAdd(&gsum[cur*DF+d], run);
      if (d==0) atomicAdd(&gcnt[cur], crun);
      run=0.f; crun=0.f; cur=g;
    }
    unsigned u = h[(size_t)i*DF+d];
    union{unsigned i; float f;} cvt; cvt.i = u<<16;
    run += cvt.f;
    crun += 1.f;
  }
  atomicAdd(&gsum[cur*DF+d], run);
  if (d==0) atomicAdd(&gcnt[cur], crun);
}

// ---------------- fused MLP head: pool-normalize + 4 layers + pred + log_softmax ----------------
__global__ __launch_bounds__(256)
void k_head(const float* __restrict__ gsum, const float* __restrict__ gcnt,
            const float* __restrict__ e1w, const float* __restrict__ e1b,
            const float* __restrict__ e2w, const float* __restrict__ e2b,
            const float* __restrict__ e3w, const float* __restrict__ e3b,
            const float* __restrict__ e4w, const float* __restrict__ e4b,
            const float* __restrict__ pw,  const float* __restrict__ pb,
            float* __restrict__ out, float* __restrict__ hidden){
  __shared__ float hg[DF];
  __shared__ float bufA[HID];
  __shared__ float bufB[HID];
  __shared__ float r0[HID], r1[HID];
  const int g = blockIdx.x, t = threadIdx.x;
  if (t<DF) hg[t] = gsum[g*DF+t] / fmaxf(gcnt[g],1.0f);
  __syncthreads();

  float acc = e1b[t];
  for (int k=0;k<DF;++k) acc += hg[k]*e1w[k*HID+t];
  float h1 = fmaxf(acc,0.f);
  hidden[g*HID+t] = h1;
  bufA[t] = h1;
  __syncthreads();

  acc = e2b[t];
  for (int k=0;k<HID;++k) acc += bufA[k]*e2w[k*HID+t];
  bufB[t] = fmaxf(acc,0.f);
  __syncthreads();

  acc = e3b[t];
  for (int k=0;k<HID;++k) acc += bufB[k]*e3w[k*HID+t];
  bufA[t] = fmaxf(acc,0.f);
  __syncthreads();

  acc = e4b[t];
  for (int k=0;k<HID;++k) acc += bufA[k]*e4w[k*HID+t];
  float h4 = fmaxf(acc,0.f);

  r0[t] = h4*pw[t*2+0];
  r1[t] = h4*pw[t*2+1];
  __syncthreads();
  for (int o=128;o>0;o>>=1){
    if (t<o){ r0[t]+=r0[t+o]; r1[t]+=r1[t+o]; }
    __syncthreads();
  }
  if (t==0){
    float y0 = r0[0]+pb[0], y1 = r1[0]+pb[1];
    float m = fmaxf(y0,y1);
    float l = m + logf(expf(y0-m)+expf(y1-m));
    out[g*2+0]=y0-l;
    out[g*2+1]=y1-l;
  }
}

extern "C" void kernel_launch(void* const* d_in, const int* in_sizes, int n_in,
                              void* d_out, int out_size, void* d_ws, size_t ws_size,
                              hipStream_t stream){
  const int* feat = (const int*)d_in[0];
  const int* src  = (const int*)d_in[1];
  const int* dst  = (const int*)d_in[2];
  const int* gid  = (const int*)d_in[3];
  const float* emb = (const float*)d_in[4];
  const float* ws0 = (const float*)d_in[5];
  const float* wn0 = (const float*)d_in[6];
  const float* b0  = (const float*)d_in[7];
  const float* ws1 = (const float*)d_in[8];
  const float* wn1 = (const float*)d_in[9];
  const float* b1  = (const float*)d_in[10];
  const float* e1w = (const float*)d_in[11];
  const float* e1b = (const float*)d_in[12];
  const float* e2w = (const float*)d_in[13];
  const float* e2b = (const float*)d_in[14];
  const float* e3w = (const float*)d_in[15];
  const float* e3b = (const float*)d_in[16];
  const float* e4w = (const float*)d_in[17];
  const float* e4b = (const float*)d_in[18];
  const float* pw  = (const float*)d_in[19];
  const float* pb  = (const float*)d_in[20];
  const int N = in_sizes[0];
  const int E = in_sizes[1];

  char* basep = (char*)d_ws;
  size_t off=0;
  auto alloc=[&](size_t bytes)->void*{
    void* p = basep+off; off=(off+bytes+255)&~(size_t)255; return p;
  };
  unsigned short* hA = (unsigned short*)alloc((size_t)N*DF*2);
  unsigned short* hB = (unsigned short*)alloc((size_t)N*DF*2);
  int*   cnt   = (int*)  alloc((size_t)N*4);
  int*   offs  = (int*)  alloc((size_t)(N+1)*4);
  int*   cursor= (int*)  alloc((size_t)N*4);
  int*   bsums = (int*)  alloc(4096);
  int*   boff  = (int*)  alloc(4096);
  int*   csr   = (int*)  alloc((size_t)E*4);
  float* gsum  = (float*)alloc((size_t)NG*DF*4);
  float* gcnt  = (float*)alloc((size_t)NG*4);
  float* out    = (float*)d_out;
  float* hidden = out + NG*2;

  hipMemsetAsync(cnt, 0, (size_t)N*4, stream);
  hipMemsetAsync(gsum, 0, (size_t)NG*DF*4, stream);
  hipMemsetAsync(gcnt, 0, (size_t)NG*4, stream);

  k_hist<<<(E+255)/256,256,0,stream>>>(dst,cnt,E);
  int nb = (N+1023)/1024;
  k_scan_tile<<<nb,256,0,stream>>>(cnt,offs,bsums,N);
  k_scan_bsums<<<1,1024,0,stream>>>(bsums,boff,nb);
  k_scan_add<<<(N+255)/256,256,0,stream>>>(offs,cursor,boff,N,E);
  k_fill<<<(E+255)/256,256,0,stream>>>(src,dst,cursor,csr,E);

  k_embed<<<(N*(DF/8)+255)/256,256,0,stream>>>(feat,emb,(unsigned*)hA,N);
  k_sage<<<(N+31)/32,256,0,stream>>>(hA,offs,csr,ws0,wn0,b0,hB,N);
  k_sage<<<(N+31)/32,256,0,stream>>>(hB,offs,csr,ws1,wn1,b1,hA,N);

  k_pool<<<(N+255)/256,128,0,stream>>>(hA,gid,gsum,gcnt,N);
  k_head<<<NG,HID,0,stream>>>(gsum,gcnt,e1w,e1b,e2w,e2b,e3w,e3b,e4w,e4b,
                              pw,pb,out,hidden);
}

// Round 4
// 488.455 us; speedup vs baseline: 3.4615x; 1.3161x over previous
//
#include <hip/hip_runtime.h>
#include <hip/hip_bf16.h>
#include <math.h>

#define DF 128
#define HID 256
#define NG 256

typedef __attribute__((ext_vector_type(8))) short s8v;    // 8 bf16 (4 VGPR)
typedef __attribute__((ext_vector_type(4))) float f32x4;  // MFMA acc

__device__ __forceinline__ float bf_lo(unsigned u){
  union{unsigned i; float f;} c; c.i = u<<16; return c.f;
}
__device__ __forceinline__ float bf_hi(unsigned u){
  union{unsigned i; float f;} c; c.i = u & 0xffff0000u; return c.f;
}
__device__ __forceinline__ unsigned pack2bf(float lo, float hi){
  unsigned a = __bfloat16_as_ushort(__float2bfloat16(lo));
  unsigned b = __bfloat16_as_ushort(__float2bfloat16(hi));
  return a | (b<<16);
}

// ---------------- CSR build ----------------
__global__ void k_hist(const int* __restrict__ dst, int* __restrict__ cnt, int E){
  int e = blockIdx.x*256 + threadIdx.x;
  if (e < E) atomicAdd(&cnt[dst[e]], 1);
}

__global__ void k_scan_tile(const int* __restrict__ cnt, int* __restrict__ offs,
                            int* __restrict__ bsums, int n){
  __shared__ int sh[256];
  int t = threadIdx.x;
  int base = blockIdx.x*1024 + t*4;
  int v0=0,v1=0,v2=0,v3=0;
  if (base+0 < n) v0 = cnt[base+0];
  if (base+1 < n) v1 = cnt[base+1];
  if (base+2 < n) v2 = cnt[base+2];
  if (base+3 < n) v3 = cnt[base+3];
  int s = v0+v1+v2+v3;
  sh[t] = s; __syncthreads();
  for (int o=1;o<256;o<<=1){
    int x = (t>=o)? sh[t-o] : 0;
    __syncthreads();
    sh[t] += x;
    __syncthreads();
  }
  int run = sh[t] - s;
  if (base+0 < n) offs[base+0] = run;
  run += v0;
  if (base+1 < n) offs[base+1] = run;
  run += v1;
  if (base+2 < n) offs[base+2] = run;
  run += v2;
  if (base+3 < n) offs[base+3] = run;
  if (t==255) bsums[blockIdx.x] = sh[255];
}

__global__ void k_scan_bsums(const int* __restrict__ bsums, int* __restrict__ boff, int nb){
  __shared__ int sh[1024];
  int t = threadIdx.x;
  int s = (t<nb)? bsums[t] : 0;
  sh[t]=s; __syncthreads();
  for (int o=1;o<1024;o<<=1){
    int x = (t>=o)? sh[t-o]:0;
    __syncthreads();
    sh[t]+=x;
    __syncthreads();
  }
  if (t<nb) boff[t] = sh[t]-s;
}

__global__ void k_scan_add(int* __restrict__ offs, int* __restrict__ cursor,
                           const int* __restrict__ boff, int n, int E){
  int i = blockIdx.x*256+threadIdx.x;
  if (i<n){
    int v = offs[i] + boff[i>>10];
    offs[i]=v; cursor[i]=v;
  }
  if (i==0 && blockIdx.x==0) offs[n]=E;
}

__global__ void k_fill(const int* __restrict__ src, const int* __restrict__ dst,
                       int* __restrict__ cursor, int* __restrict__ csr_src, int E){
  int e = blockIdx.x*256+threadIdx.x;
  if (e<E){
    int pos = atomicAdd(&cursor[dst[e]],1);
    csr_src[pos]=src[e];
  }
}

// ---------------- weight prep: Wt[layer][n][k] bf16, k = [self(128) | neigh(128)] ----------------
__global__ void k_prepw(const float* __restrict__ ws0, const float* __restrict__ wn0,
                        const float* __restrict__ ws1, const float* __restrict__ wn1,
                        unsigned short* __restrict__ wt){
  int n = blockIdx.x & 127;
  int layer = blockIdx.x >> 7;
  int k = threadIdx.x;                 // 0..255
  const float* ws = layer? ws1 : ws0;
  const float* wn = layer? wn1 : wn0;
  float v = (k<128)? ws[k*DF+n] : wn[(k-128)*DF+n];
  wt[((size_t)layer*DF + n)*256 + k] = __bfloat16_as_ushort(__float2bfloat16(v));
}

// ---------------- embedding gather -> bf16 h ----------------
__global__ void k_embed(const int* __restrict__ feat, const float* __restrict__ emb,
                        unsigned* __restrict__ h4, int N){
  int idx = blockIdx.x*256+threadIdx.x;
  int total = N*(DF/8);
  if (idx<total){
    int i = idx/(DF/8), c = idx%(DF/8);
    const float4* e4 = (const float4*)emb;
    size_t rb = (size_t)feat[i]*(DF/4);
    float4 v0 = e4[rb + c*2], v1 = e4[rb + c*2+1];
    uint4 o;
    o.x = pack2bf(v0.x,v0.y); o.y = pack2bf(v0.z,v0.w);
    o.z = pack2bf(v1.x,v1.y); o.w = pack2bf(v1.z,v1.w);
    ((uint4*)h4)[idx] = o;
  }
}

// ---------------- fused SAGE layer: gather-mean + MFMA GEMM + bias + relu ----------------
// block = 256 thr (4 waves), 32 nodes. A-tile [32][256] bf16 in LDS (XOR-swizzled),
// B (Wt) register-resident per wave. K=256 fused [self|neigh] x [ws;wn].
__global__ __launch_bounds__(256,4)
void k_sage(const unsigned short* __restrict__ h_in,
            const int* __restrict__ offs, const int* __restrict__ csr,
            const unsigned short* __restrict__ wt,   // [128][256] bf16 (row n, col k)
            const float* __restrict__ bias, unsigned short* __restrict__ h_out, int N){
  __shared__ __align__(16) unsigned short s_ab[32*256];   // 16KB
  const int t = threadIdx.x;
  const int node0 = blockIdx.x*32;
  const uint4* hin4 = (const uint4*)h_in;   // 16 uint4 per row

  // ---- self rows: bf16 copy into A-tile cols 0..127, swizzled
  for (int idx = t; idx < 512; idx += 256){
    int nn = idx>>4, c = idx&15;
    int node = node0+nn;
    uint4 q = make_uint4(0,0,0,0);
    if (node<N) q = hin4[(size_t)node*16 + c];
    int byte = (nn*512 + c*16) ^ ((nn&7)<<4);
    *(uint4*)((char*)s_ab + byte) = q;
  }

  // ---- neighbor mean (thread: node t>>3, 16-col chunk t&7), f32 accum, 2-edge unroll
  {
    const int nn = t>>3, c = t&7;
    const int node = node0+nn;
    float a[16];
    #pragma unroll
    for (int j=0;j<16;j++) a[j]=0.f;
    if (node<N){
      int e0=offs[node], e1=offs[node+1];
      int deg = e1-e0;
      if (deg>0){
        int e=e0;
        for (; e+2<=e1; e+=2){
          int s0=csr[e], s1=csr[e+1];
          const uint4* p0 = hin4 + (size_t)s0*16 + c*2;
          const uint4* p1 = hin4 + (size_t)s1*16 + c*2;
          uint4 q0=p0[0], q1=p0[1], q2=p1[0], q3=p1[1];
          a[0]+=bf_lo(q0.x); a[1]+=bf_hi(q0.x); a[2]+=bf_lo(q0.y); a[3]+=bf_hi(q0.y);
          a[4]+=bf_lo(q0.z); a[5]+=bf_hi(q0.z); a[6]+=bf_lo(q0.w); a[7]+=bf_hi(q0.w);
          a[8]+=bf_lo(q1.x); a[9]+=bf_hi(q1.x); a[10]+=bf_lo(q1.y); a[11]+=bf_hi(q1.y);
          a[12]+=bf_lo(q1.z); a[13]+=bf_hi(q1.z); a[14]+=bf_lo(q1.w); a[15]+=bf_hi(q1.w);
          a[0]+=bf_lo(q2.x); a[1]+=bf_hi(q2.x); a[2]+=bf_lo(q2.y); a[3]+=bf_hi(q2.y);
          a[4]+=bf_lo(q2.z); a[5]+=bf_hi(q2.z); a[6]+=bf_lo(q2.w); a[7]+=bf_hi(q2.w);
          a[8]+=bf_lo(q3.x); a[9]+=bf_hi(q3.x); a[10]+=bf_lo(q3.y); a[11]+=bf_hi(q3.y);
          a[12]+=bf_lo(q3.z); a[13]+=bf_hi(q3.z); a[14]+=bf_lo(q3.w); a[15]+=bf_hi(q3.w);
        }
        if (e<e1){
          int s0=csr[e];
          const uint4* p0 = hin4 + (size_t)s0*16 + c*2;
          uint4 q0=p0[0], q1=p0[1];
          a[0]+=bf_lo(q0.x); a[1]+=bf_hi(q0.x); a[2]+=bf_lo(q0.y); a[3]+=bf_hi(q0.y);
          a[4]+=bf_lo(q0.z); a[5]+=bf_hi(q0.z); a[6]+=bf_lo(q0.w); a[7]+=bf_hi(q0.w);
          a[8]+=bf_lo(q1.x); a[9]+=bf_hi(q1.x); a[10]+=bf_lo(q1.y); a[11]+=bf_hi(q1.y);
          a[12]+=bf_lo(q1.z); a[13]+=bf_hi(q1.z); a[14]+=bf_lo(q1.w); a[15]+=bf_hi(q1.w);
        }
        float inv = 1.0f/(float)deg;
        #pragma unroll
        for (int j=0;j<16;j++) a[j]*=inv;
      }
    }
    unsigned pk[8];
    #pragma unroll
    for (int j=0;j<8;j++) pk[j] = pack2bf(a[2*j],a[2*j+1]);
    int byte0 = nn*512 + 256 + c*32;
    int sw = (nn&7)<<4;
    *(uint4*)((char*)s_ab + ((byte0   )^sw)) = make_uint4(pk[0],pk[1],pk[2],pk[3]);
    *(uint4*)((char*)s_ab + ((byte0+16)^sw)) = make_uint4(pk[4],pk[5],pk[6],pk[7]);
  }

  // ---- B fragments: wave wv owns n-tiles {2wv, 2wv+1}; lane l: col lr, k-group kg
  const int wv = t>>6;
  const int lr = t&15;
  const int kg = (t&63)>>4;
  s8v bfrag[2][8];
  {
    const s8v* wt8 = (const s8v*)wt;  // 32 chunks of 8 per 256-col row
    #pragma unroll
    for (int ks=0; ks<8; ks++){
      int kb = ks*4 + kg;
      bfrag[0][ks] = wt8[(size_t)(wv*32     + lr)*32 + kb];
      bfrag[1][ks] = wt8[(size_t)(wv*32 + 16+ lr)*32 + kb];
    }
  }
  __syncthreads();

  // ---- MFMA main loop: acc[m][n] for m-tiles 0..1, this wave's 2 n-tiles
  f32x4 acc00={0,0,0,0}, acc01={0,0,0,0}, acc10={0,0,0,0}, acc11={0,0,0,0};
  #pragma unroll
  for (int ks=0; ks<8; ks++){
    int cb = ks*64 + kg*16;
    int r0 = lr, r1 = 16+lr;
    s8v a0 = *(const s8v*)((const char*)s_ab + ((r0*512+cb) ^ ((r0&7)<<4)));
    s8v a1 = *(const s8v*)((const char*)s_ab + ((r1*512+cb) ^ ((r1&7)<<4)));
    acc00 = __builtin_amdgcn_mfma_f32_16x16x32_bf16(a0, bfrag[0][ks], acc00, 0,0,0);
    acc01 = __builtin_amdgcn_mfma_f32_16x16x32_bf16(a0, bfrag[1][ks], acc01, 0,0,0);
    acc10 = __builtin_amdgcn_mfma_f32_16x16x32_bf16(a1, bfrag[0][ks], acc10, 0,0,0);
    acc11 = __builtin_amdgcn_mfma_f32_16x16x32_bf16(a1, bfrag[1][ks], acc11, 0,0,0);
  }
  __syncthreads();   // all reads of s_ab done before reuse

  // ---- epilogue: acc -> LDS f32 [32][128] -> bias+relu -> bf16 coalesced store
  float* cbuf = (float*)s_ab;   // exactly 16KB
  #pragma unroll
  for (int r=0;r<4;r++){
    int row0 = kg*4 + r;
    cbuf[(row0   )*DF + wv*32      + lr] = acc00[r];
    cbuf[(row0   )*DF + wv*32 + 16 + lr] = acc01[r];
    cbuf[(row0+16)*DF + wv*32      + lr] = acc10[r];
    cbuf[(row0+16)*DF + wv*32 + 16 + lr] = acc11[r];
  }
  __syncthreads();
  {
    int row = t>>3, c0 = (t&7)*16;
    int node = node0+row;
    if (node<N){
      unsigned pk[8];
      #pragma unroll
      for (int j=0;j<8;j++){
        float x0 = fmaxf(cbuf[row*DF + c0 + 2*j  ] + bias[c0+2*j  ], 0.f);
        float x1 = fmaxf(cbuf[row*DF + c0 + 2*j+1] + bias[c0+2*j+1], 0.f);
        pk[j] = pack2bf(x0,x1);
      }
      uint4* dstp = (uint4*)&h_out[(size_t)node*DF + c0];
      dstp[0] = make_uint4(pk[0],pk[1],pk[2],pk[3]);
      dstp[1] = make_uint4(pk[4],pk[5],pk[6],pk[7]);
    }
  }
}

// ---------------- graph mean pool (graph_id sorted, bf16 h) ----------------
__global__ void k_pool(const unsigned short* __restrict__ h, const int* __restrict__ gid,
                       float* __restrict__ gsum, float* __restrict__ gcnt, int N){
  int d = threadIdx.x; // 128
  int i0 = blockIdx.x*256;
  if (i0>=N) return;
  int i1 = i0+256; if (i1>N) i1=N;
  int cur = gid[i0];
  float run=0.f, crun=0.f;
  for (int i=i0;i<i1;++i){
    int g = gid[i];
    if (g!=cur){
      atomicAdd(&gsum[cur*DF+d], run);
      if (d==0) atomicAdd(&gcnt[cur], crun);
      run=0.f; crun=0.f; cur=g;
    }
    unsigned u = h[(size_t)i*DF+d];
    union{unsigned i; float f;} cvt; cvt.i = u<<16;
    run += cvt.f;
    crun += 1.f;
  }
  atomicAdd(&gsum[cur*DF+d], run);
  if (d==0) atomicAdd(&gcnt[cur], crun);
}

// ---------------- fused MLP head ----------------
__global__ __launch_bounds__(256)
void k_head(const float* __restrict__ gsum, const float* __restrict__ gcnt,
            const float* __restrict__ e1w, const float* __restrict__ e1b,
            const float* __restrict__ e2w, const float* __restrict__ e2b,
            const float* __restrict__ e3w, const float* __restrict__ e3b,
            const float* __restrict__ e4w, const float* __restrict__ e4b,
            const float* __restrict__ pw,  const float* __restrict__ pb,
            float* __restrict__ out, float* __restrict__ hidden){
  __shared__ float hg[DF];
  __shared__ float bufA[HID];
  __shared__ float bufB[HID];
  __shared__ float r0[HID], r1[HID];
  const int g = blockIdx.x, t = threadIdx.x;
  if (t<DF) hg[t] = gsum[g*DF+t] / fmaxf(gcnt[g],1.0f);
  __syncthreads();

  float acc = e1b[t];
  for (int k=0;k<DF;++k) acc += hg[k]*e1w[k*HID+t];
  float h1 = fmaxf(acc,0.f);
  hidden[g*HID+t] = h1;
  bufA[t] = h1;
  __syncthreads();

  acc = e2b[t];
  for (int k=0;k<HID;++k) acc += bufA[k]*e2w[k*HID+t];
  bufB[t] = fmaxf(acc,0.f);
  __syncthreads();

  acc = e3b[t];
  for (int k=0;k<HID;++k) acc += bufB[k]*e3w[k*HID+t];
  bufA[t] = fmaxf(acc,0.f);
  __syncthreads();

  acc = e4b[t];
  for (int k=0;k<HID;++k) acc += bufA[k]*e4w[k*HID+t];
  float h4 = fmaxf(acc,0.f);

  r0[t] = h4*pw[t*2+0];
  r1[t] = h4*pw[t*2+1];
  __syncthreads();
  for (int o=128;o>0;o>>=1){
    if (t<o){ r0[t]+=r0[t+o]; r1[t]+=r1[t+o]; }
    __syncthreads();
  }
  if (t==0){
    float y0 = r0[0]+pb[0], y1 = r1[0]+pb[1];
    float m = fmaxf(y0,y1);
    float l = m + logf(expf(y0-m)+expf(y1-m));
    out[g*2+0]=y0-l;
    out[g*2+1]=y1-l;
  }
}

extern "C" void kernel_launch(void* const* d_in, const int* in_sizes, int n_in,
                              void* d_out, int out_size, void* d_ws, size_t ws_size,
                              hipStream_t stream){
  const int* feat = (const int*)d_in[0];
  const int* src  = (const int*)d_in[1];
  const int* dst  = (const int*)d_in[2];
  const int* gid  = (const int*)d_in[3];
  const float* emb = (const float*)d_in[4];
  const float* ws0 = (const float*)d_in[5];
  const float* wn0 = (const float*)d_in[6];
  const float* b0  = (const float*)d_in[7];
  const float* ws1 = (const float*)d_in[8];
  const float* wn1 = (const float*)d_in[9];
  const float* b1  = (const float*)d_in[10];
  const float* e1w = (const float*)d_in[11];
  const float* e1b = (const float*)d_in[12];
  const float* e2w = (const float*)d_in[13];
  const float* e2b = (const float*)d_in[14];
  const float* e3w = (const float*)d_in[15];
  const float* e3b = (const float*)d_in[16];
  const float* e4w = (const float*)d_in[17];
  const float* e4b = (const float*)d_in[18];
  const float* pw  = (const float*)d_in[19];
  const float* pb  = (const float*)d_in[20];
  const int N = in_sizes[0];
  const int E = in_sizes[1];

  char* basep = (char*)d_ws;
  size_t off=0;
  auto alloc=[&](size_t bytes)->void*{
    void* p = basep+off; off=(off+bytes+255)&~(size_t)255; return p;
  };
  unsigned short* hA = (unsigned short*)alloc((size_t)N*DF*2);
  unsigned short* hB = (unsigned short*)alloc((size_t)N*DF*2);
  int*   cnt   = (int*)  alloc((size_t)N*4);
  int*   offs  = (int*)  alloc((size_t)(N+1)*4);
  int*   cursor= (int*)  alloc((size_t)N*4);
  int*   bsums = (int*)  alloc(4096);
  int*   boff  = (int*)  alloc(4096);
  int*   csr   = (int*)  alloc((size_t)E*4);
  unsigned short* wtb = (unsigned short*)alloc((size_t)2*DF*256*2);
  float* gsum  = (float*)alloc((size_t)NG*DF*4);
  float* gcnt  = (float*)alloc((size_t)NG*4);
  float* out    = (float*)d_out;
  float* hidden = out + NG*2;

  hipMemsetAsync(cnt, 0, (size_t)N*4, stream);
  hipMemsetAsync(gsum, 0, (size_t)NG*DF*4, stream);
  hipMemsetAsync(gcnt, 0, (size_t)NG*4, stream);

  k_hist<<<(E+255)/256,256,0,stream>>>(dst,cnt,E);
  int nb = (N+1023)/1024;
  k_scan_tile<<<nb,256,0,stream>>>(cnt,offs,bsums,N);
  k_scan_bsums<<<1,1024,0,stream>>>(bsums,boff,nb);
  k_scan_add<<<(N+255)/256,256,0,stream>>>(offs,cursor,boff,N,E);
  k_fill<<<(E+255)/256,256,0,stream>>>(src,dst,cursor,csr,E);
  k_prepw<<<256,256,0,stream>>>(ws0,wn0,ws1,wn1,wtb);

  k_embed<<<(N*(DF/8)+255)/256,256,0,stream>>>(feat,emb,(unsigned*)hA,N);
  k_sage<<<(N+31)/32,256,0,stream>>>(hA,offs,csr,wtb,          b0,hB,N);
  k_sage<<<(N+31)/32,256,0,stream>>>(hB,offs,csr,wtb+DF*256,   b1,hA,N);

  k_pool<<<(N+255)/256,128,0,stream>>>(hA,gid,gsum,gcnt,N);
  k_head<<<NG,HID,0,stream>>>(gsum,gcnt,e1w,e1b,e2w,e2b,e3w,e3b,e4w,e4b,
                              pw,pb,out,hidden);
}

// Round 5
// 344.517 us; speedup vs baseline: 4.9077x; 1.4178x over previous
//
#include <hip/hip_runtime.h>
#include <hip/hip_bf16.h>
#include <math.h>

#define DF 128
#define HID 256
#define NG 256

typedef __attribute__((ext_vector_type(8))) short s8v;    // 8 bf16 (4 VGPR)
typedef __attribute__((ext_vector_type(4))) float f32x4;  // MFMA acc

__device__ __forceinline__ float bf_lo(unsigned u){
  union{unsigned i; float f;} c; c.i = u<<16; return c.f;
}
__device__ __forceinline__ float bf_hi(unsigned u){
  union{unsigned i; float f;} c; c.i = u & 0xffff0000u; return c.f;
}
__device__ __forceinline__ unsigned pack2bf(float lo, float hi){
  unsigned a = __bfloat16_as_ushort(__float2bfloat16(lo));
  unsigned b = __bfloat16_as_ushort(__float2bfloat16(hi));
  return a | (b<<16);
}

// =============== binned CSR build (kills 4B-scatter write amplification) ===============
// bucket = dst >> 9 (512 nodes/bucket, NBK = ceil(N/512) <= 256 for N <= 131072)

__global__ void k_bhist(const int* __restrict__ dst, int* __restrict__ gb, int E){
  __shared__ int hist[256];
  int t = threadIdx.x;
  hist[t]=0; __syncthreads();
  for (int i = blockIdx.x*256+t; i < E; i += gridDim.x*256)
    atomicAdd(&hist[dst[i]>>9], 1);
  __syncthreads();
  if (hist[t]) atomicAdd(&gb[t], hist[t]);
}

__global__ void k_bscan(const int* __restrict__ gb, int* __restrict__ bbase,
                        int* __restrict__ bcur, int E){
  __shared__ int sh[256];
  int t = threadIdx.x;
  int v = gb[t];
  sh[t]=v; __syncthreads();
  for (int o=1;o<256;o<<=1){
    int x = (t>=o)? sh[t-o] : 0;
    __syncthreads();
    sh[t]+=x;
    __syncthreads();
  }
  int ex = sh[t]-v;
  bbase[t]=ex; bcur[t]=ex;
  if (t==255) bbase[256]=E;
}

// block-local binning: each block reserves a contiguous range per bucket (1 atomic
// per bucket), then appends its edges as (src,dst) pairs -> dense-in-time writes.
__global__ __launch_bounds__(256)
void k_bplace(const int* __restrict__ src, const int* __restrict__ dst,
              int* __restrict__ bcur, uint2* __restrict__ pairs, int E){
  __shared__ int hist[256];
  __shared__ int base[256];
  __shared__ int cur[256];
  const int t = threadIdx.x;
  const int CH = (E + gridDim.x - 1)/gridDim.x;
  const int s = blockIdx.x*CH;
  int e = s+CH; if (e>E) e=E;
  if (s>=E) return;
  hist[t]=0; __syncthreads();
  for (int i=s+t; i<e; i+=256) atomicAdd(&hist[dst[i]>>9],1);
  __syncthreads();
  if (hist[t]){ base[t]=atomicAdd(&bcur[t],hist[t]); }
  cur[t]=0;
  __syncthreads();
  for (int i=s+t; i<e; i+=256){
    int d = dst[i];
    int bk = d>>9;
    int r = atomicAdd(&cur[bk],1);
    pairs[base[bk]+r] = make_uint2((unsigned)src[i],(unsigned)d);
  }
}

// one block per bucket: per-node counts -> LDS scan -> coalesced offs write ->
// scatter src into the bucket's contiguous (L2-hot) csr region.
__global__ __launch_bounds__(256)
void k_bcsr(const uint2* __restrict__ pairs, const int* __restrict__ bbase,
            int* __restrict__ offs, int* __restrict__ csr, int N, int E){
  __shared__ int ncnt[512];
  __shared__ int noff[512];
  __shared__ int sh[256];
  const int t = threadIdx.x;
  const int b = blockIdx.x;
  const int nb0 = b<<9;
  const int s = bbase[b], e = bbase[b+1];
  ncnt[t]=0; ncnt[t+256]=0;
  __syncthreads();
  for (int i=s+t; i<e; i+=256) atomicAdd(&ncnt[(int)pairs[i].y - nb0], 1);
  __syncthreads();
  int v0 = ncnt[2*t], v1 = ncnt[2*t+1];
  int v = v0+v1;
  sh[t]=v; __syncthreads();
  for (int o=1;o<256;o<<=1){
    int x=(t>=o)?sh[t-o]:0;
    __syncthreads();
    sh[t]+=x;
    __syncthreads();
  }
  int ex = sh[t]-v;
  noff[2*t]=ex; noff[2*t+1]=ex+v0;
  __syncthreads();
  {
    int n0 = nb0 + t;
    if (n0 < N) offs[n0] = s + noff[t];
    int n1 = nb0 + t + 256;
    if (n1 < N) offs[n1] = s + noff[t+256];
    if (b == gridDim.x-1 && t==0) offs[N] = E;
  }
  ncnt[t]=0; ncnt[t+256]=0;
  __syncthreads();
  for (int i=s+t; i<e; i+=256){
    uint2 p = pairs[i];
    int d = (int)p.y - nb0;
    int r = atomicAdd(&ncnt[d],1);
    csr[s + noff[d] + r] = (int)p.x;
  }
}

// ---------------- weight prep: Wt[layer][n][k] bf16, k = [self(128) | neigh(128)] ----------------
__global__ void k_prepw(const float* __restrict__ ws0, const float* __restrict__ wn0,
                        const float* __restrict__ ws1, const float* __restrict__ wn1,
                        unsigned short* __restrict__ wt){
  int n = blockIdx.x & 127;
  int layer = blockIdx.x >> 7;
  int k = threadIdx.x;                 // 0..255
  const float* ws = layer? ws1 : ws0;
  const float* wn = layer? wn1 : wn0;
  float v = (k<128)? ws[k*DF+n] : wn[(k-128)*DF+n];
  wt[((size_t)layer*DF + n)*256 + k] = __bfloat16_as_ushort(__float2bfloat16(v));
}

// ---------------- embedding gather -> bf16 h ----------------
__global__ void k_embed(const int* __restrict__ feat, const float* __restrict__ emb,
                        unsigned* __restrict__ h4, int N){
  int idx = blockIdx.x*256+threadIdx.x;
  int total = N*(DF/8);
  if (idx<total){
    int i = idx/(DF/8), c = idx%(DF/8);
    const float4* e4 = (const float4*)emb;
    size_t rb = (size_t)feat[i]*(DF/4);
    float4 v0 = e4[rb + c*2], v1 = e4[rb + c*2+1];
    uint4 o;
    o.x = pack2bf(v0.x,v0.y); o.y = pack2bf(v0.z,v0.w);
    o.z = pack2bf(v1.x,v1.y); o.w = pack2bf(v1.z,v1.w);
    ((uint4*)h4)[idx] = o;
  }
}

// ---------------- fused SAGE layer: gather-mean + MFMA GEMM + bias + relu ----------------
// block = 256 thr (4 waves), 32 nodes. A-tile [32][256] bf16 in LDS (XOR-swizzled).
// B loaded in two K=128 halves (peak VGPR lower -> 6 waves/SIMD).
__global__ __launch_bounds__(256,6)
void k_sage(const unsigned short* __restrict__ h_in,
            const int* __restrict__ offs, const int* __restrict__ csr,
            const unsigned short* __restrict__ wt,   // [128][256] bf16 (row n, col k)
            const float* __restrict__ bias, unsigned short* __restrict__ h_out, int N){
  __shared__ __align__(16) unsigned short s_ab[32*256];   // 16KB
  const int t = threadIdx.x;
  const int node0 = blockIdx.x*32;
  const uint4* hin4 = (const uint4*)h_in;   // 16 uint4 per row

  // ---- self rows: bf16 copy into A-tile cols 0..127, swizzled
  for (int idx = t; idx < 512; idx += 256){
    int nn = idx>>4, c = idx&15;
    int node = node0+nn;
    uint4 q = make_uint4(0,0,0,0);
    if (node<N) q = hin4[(size_t)node*16 + c];
    int byte = (nn*512 + c*16) ^ ((nn&7)<<4);
    *(uint4*)((char*)s_ab + byte) = q;
  }

  // ---- neighbor mean (thread: node t>>3, 16-col chunk t&7), f32 accum, 2-edge unroll
  {
    const int nn = t>>3, c = t&7;
    const int node = node0+nn;
    float a[16];
    #pragma unroll
    for (int j=0;j<16;j++) a[j]=0.f;
    if (node<N){
      int e0=offs[node], e1=offs[node+1];
      int deg = e1-e0;
      if (deg>0){
        int e=e0;
        for (; e+2<=e1; e+=2){
          int s0=csr[e], s1=csr[e+1];
          const uint4* p0 = hin4 + (size_t)s0*16 + c*2;
          const uint4* p1 = hin4 + (size_t)s1*16 + c*2;
          uint4 q0=p0[0], q1=p0[1], q2=p1[0], q3=p1[1];
          a[0]+=bf_lo(q0.x); a[1]+=bf_hi(q0.x); a[2]+=bf_lo(q0.y); a[3]+=bf_hi(q0.y);
          a[4]+=bf_lo(q0.z); a[5]+=bf_hi(q0.z); a[6]+=bf_lo(q0.w); a[7]+=bf_hi(q0.w);
          a[8]+=bf_lo(q1.x); a[9]+=bf_hi(q1.x); a[10]+=bf_lo(q1.y); a[11]+=bf_hi(q1.y);
          a[12]+=bf_lo(q1.z); a[13]+=bf_hi(q1.z); a[14]+=bf_lo(q1.w); a[15]+=bf_hi(q1.w);
          a[0]+=bf_lo(q2.x); a[1]+=bf_hi(q2.x); a[2]+=bf_lo(q2.y); a[3]+=bf_hi(q2.y);
          a[4]+=bf_lo(q2.z); a[5]+=bf_hi(q2.z); a[6]+=bf_lo(q2.w); a[7]+=bf_hi(q2.w);
          a[8]+=bf_lo(q3.x); a[9]+=bf_hi(q3.x); a[10]+=bf_lo(q3.y); a[11]+=bf_hi(q3.y);
          a[12]+=bf_lo(q3.z); a[13]+=bf_hi(q3.z); a[14]+=bf_lo(q3.w); a[15]+=bf_hi(q3.w);
        }
        if (e<e1){
          int s0=csr[e];
          const uint4* p0 = hin4 + (size_t)s0*16 + c*2;
          uint4 q0=p0[0], q1=p0[1];
          a[0]+=bf_lo(q0.x); a[1]+=bf_hi(q0.x); a[2]+=bf_lo(q0.y); a[3]+=bf_hi(q0.y);
          a[4]+=bf_lo(q0.z); a[5]+=bf_hi(q0.z); a[6]+=bf_lo(q0.w); a[7]+=bf_hi(q0.w);
          a[8]+=bf_lo(q1.x); a[9]+=bf_hi(q1.x); a[10]+=bf_lo(q1.y); a[11]+=bf_hi(q1.y);
          a[12]+=bf_lo(q1.z); a[13]+=bf_hi(q1.z); a[14]+=bf_lo(q1.w); a[15]+=bf_hi(q1.w);
        }
        float inv = 1.0f/(float)deg;
        #pragma unroll
        for (int j=0;j<16;j++) a[j]*=inv;
      }
    }
    unsigned pk[8];
    #pragma unroll
    for (int j=0;j<8;j++) pk[j] = pack2bf(a[2*j],a[2*j+1]);
    int byte0 = nn*512 + 256 + c*32;
    int sw = (nn&7)<<4;
    *(uint4*)((char*)s_ab + ((byte0   )^sw)) = make_uint4(pk[0],pk[1],pk[2],pk[3]);
    *(uint4*)((char*)s_ab + ((byte0+16)^sw)) = make_uint4(pk[4],pk[5],pk[6],pk[7]);
  }

  const int wv = t>>6;
  const int lr = t&15;
  const int kg = (t&63)>>4;
  __syncthreads();

  // ---- MFMA main loop, B loaded per K-half from global (L2-resident)
  f32x4 acc00={0,0,0,0}, acc01={0,0,0,0}, acc10={0,0,0,0}, acc11={0,0,0,0};
  const s8v* wt8 = (const s8v*)wt;  // 32 chunks of 8 per 256-col row
  #pragma unroll
  for (int kh=0; kh<2; kh++){
    s8v bfrag[2][4];
    #pragma unroll
    for (int ks=0; ks<4; ks++){
      int kb = (kh*4+ks)*4 + kg;
      bfrag[0][ks] = wt8[(size_t)(wv*32     + lr)*32 + kb];
      bfrag[1][ks] = wt8[(size_t)(wv*32 + 16+ lr)*32 + kb];
    }
    #pragma unroll
    for (int ks=0; ks<4; ks++){
      int cb = (kh*4+ks)*64 + kg*16;
      int r0 = lr, r1 = 16+lr;
      s8v a0 = *(const s8v*)((const char*)s_ab + ((r0*512+cb) ^ ((r0&7)<<4)));
      s8v a1 = *(const s8v*)((const char*)s_ab + ((r1*512+cb) ^ ((r1&7)<<4)));
      acc00 = __builtin_amdgcn_mfma_f32_16x16x32_bf16(a0, bfrag[0][ks], acc00, 0,0,0);
      acc01 = __builtin_amdgcn_mfma_f32_16x16x32_bf16(a0, bfrag[1][ks], acc01, 0,0,0);
      acc10 = __builtin_amdgcn_mfma_f32_16x16x32_bf16(a1, bfrag[0][ks], acc10, 0,0,0);
      acc11 = __builtin_amdgcn_mfma_f32_16x16x32_bf16(a1, bfrag[1][ks], acc11, 0,0,0);
    }
  }
  __syncthreads();   // all reads of s_ab done before reuse

  // ---- epilogue: acc -> LDS f32 [32][128] -> bias+relu -> bf16 coalesced store
  float* cbuf = (float*)s_ab;   // exactly 16KB
  #pragma unroll
  for (int r=0;r<4;r++){
    int row0 = kg*4 + r;
    cbuf[(row0   )*DF + wv*32      + lr] = acc00[r];
    cbuf[(row0   )*DF + wv*32 + 16 + lr] = acc01[r];
    cbuf[(row0+16)*DF + wv*32      + lr] = acc10[r];
    cbuf[(row0+16)*DF + wv*32 + 16 + lr] = acc11[r];
  }
  __syncthreads();
  {
    int row = t>>3, c0 = (t&7)*16;
    int node = node0+row;
    if (node<N){
      unsigned pk[8];
      #pragma unroll
      for (int j=0;j<8;j++){
        float x0 = fmaxf(cbuf[row*DF + c0 + 2*j  ] + bias[c0+2*j  ], 0.f);
        float x1 = fmaxf(cbuf[row*DF + c0 + 2*j+1] + bias[c0+2*j+1], 0.f);
        pk[j] = pack2bf(x0,x1);
      }
      uint4* dstp = (uint4*)&h_out[(size_t)node*DF + c0];
      dstp[0] = make_uint4(pk[0],pk[1],pk[2],pk[3]);
      dstp[1] = make_uint4(pk[4],pk[5],pk[6],pk[7]);
    }
  }
}

// ---------------- graph mean pool (graph_id sorted, bf16 h) ----------------
__global__ void k_pool(const unsigned short* __restrict__ h, const int* __restrict__ gid,
                       float* __restrict__ gsum, float* __restrict__ gcnt, int N){
  int d = threadIdx.x; // 128
  int i0 = blockIdx.x*256;
  if (i0>=N) return;
  int i1 = i0+256; if (i1>N) i1=N;
  int cur = gid[i0];
  float run=0.f, crun=0.f;
  for (int i=i0;i<i1;++i){
    int g = gid[i];
    if (g!=cur){
      atomicAdd(&gsum[cur*DF+d], run);
      if (d==0) atomicAdd(&gcnt[cur], crun);
      run=0.f; crun=0.f; cur=g;
    }
    unsigned u = h[(size_t)i*DF+d];
    union{unsigned i; float f;} cvt; cvt.i = u<<16;
    run += cvt.f;
    crun += 1.f;
  }
  atomicAdd(&gsum[cur*DF+d], run);
  if (d==0) atomicAdd(&gcnt[cur], crun);
}

// ---------------- fused MLP head ----------------
__global__ __launch_bounds__(256)
void k_head(const float* __restrict__ gsum, const float* __restrict__ gcnt,
            const float* __restrict__ e1w, const float* __restrict__ e1b,
            const float* __restrict__ e2w, const float* __restrict__ e2b,
            const float* __restrict__ e3w, const float* __restrict__ e3b,
            const float* __restrict__ e4w, const float* __restrict__ e4b,
            const float* __restrict__ pw,  const float* __restrict__ pb,
            float* __restrict__ out, float* __restrict__ hidden){
  __shared__ float hg[DF];
  __shared__ float bufA[HID];
  __shared__ float bufB[HID];
  __shared__ float r0[HID], r1[HID];
  const int g = blockIdx.x, t = threadIdx.x;
  if (t<DF) hg[t] = gsum[g*DF+t] / fmaxf(gcnt[g],1.0f);
  __syncthreads();

  float acc = e1b[t];
  for (int k=0;k<DF;++k) acc += hg[k]*e1w[k*HID+t];
  float h1 = fmaxf(acc,0.f);
  hidden[g*HID+t] = h1;
  bufA[t] = h1;
  __syncthreads();

  acc = e2b[t];
  for (int k=0;k<HID;++k) acc += bufA[k]*e2w[k*HID+t];
  bufB[t] = fmaxf(acc,0.f);
  __syncthreads();

  acc = e3b[t];
  for (int k=0;k<HID;++k) acc += bufB[k]*e3w[k*HID+t];
  bufA[t] = fmaxf(acc,0.f);
  __syncthreads();

  acc = e4b[t];
  for (int k=0;k<HID;++k) acc += bufA[k]*e4w[k*HID+t];
  float h4 = fmaxf(acc,0.f);

  r0[t] = h4*pw[t*2+0];
  r1[t] = h4*pw[t*2+1];
  __syncthreads();
  for (int o=128;o>0;o>>=1){
    if (t<o){ r0[t]+=r0[t+o]; r1[t]+=r1[t+o]; }
    __syncthreads();
  }
  if (t==0){
    float y0 = r0[0]+pb[0], y1 = r1[0]+pb[1];
    float m = fmaxf(y0,y1);
    float l = m + logf(expf(y0-m)+expf(y1-m));
    out[g*2+0]=y0-l;
    out[g*2+1]=y1-l;
  }
}

extern "C" void kernel_launch(void* const* d_in, const int* in_sizes, int n_in,
                              void* d_out, int out_size, void* d_ws, size_t ws_size,
                              hipStream_t stream){
  const int* feat = (const int*)d_in[0];
  const int* src  = (const int*)d_in[1];
  const int* dst  = (const int*)d_in[2];
  const int* gid  = (const int*)d_in[3];
  const float* emb = (const float*)d_in[4];
  const float* ws0 = (const float*)d_in[5];
  const float* wn0 = (const float*)d_in[6];
  const float* b0  = (const float*)d_in[7];
  const float* ws1 = (const float*)d_in[8];
  const float* wn1 = (const float*)d_in[9];
  const float* b1  = (const float*)d_in[10];
  const float* e1w = (const float*)d_in[11];
  const float* e1b = (const float*)d_in[12];
  const float* e2w = (const float*)d_in[13];
  const float* e2b = (const float*)d_in[14];
  const float* e3w = (const float*)d_in[15];
  const float* e3b = (const float*)d_in[16];
  const float* e4w = (const float*)d_in[17];
  const float* e4b = (const float*)d_in[18];
  const float* pw  = (const float*)d_in[19];
  const float* pb  = (const float*)d_in[20];
  const int N = in_sizes[0];
  const int E = in_sizes[1];

  char* basep = (char*)d_ws;
  size_t off=0;
  auto alloc=[&](size_t bytes)->void*{
    void* p = basep+off; off=(off+bytes+255)&~(size_t)255; return p;
  };
  unsigned short* hA = (unsigned short*)alloc((size_t)N*DF*2);
  unsigned short* hB = (unsigned short*)alloc((size_t)N*DF*2);
  int*   offs  = (int*)  alloc((size_t)(N+1)*4);
  int*   csr   = (int*)  alloc((size_t)E*4);
  int*   gb    = (int*)  alloc(1024);
  int*   bbase = (int*)  alloc(1028+60);   // 257 ints
  int*   bcur  = (int*)  alloc(1024);
  unsigned short* wtb = (unsigned short*)alloc((size_t)2*DF*256*2);
  float* gsum  = (float*)alloc((size_t)NG*DF*4);
  float* gcnt  = (float*)alloc((size_t)NG*4);
  // pairs aliases hB: consumed by k_bcsr strictly before k_sage writes hB
  uint2* pairs = (uint2*)hB;
  float* out    = (float*)d_out;
  float* hidden = out + NG*2;

  hipMemsetAsync(gb, 0, 1024, stream);
  hipMemsetAsync(gsum, 0, (size_t)NG*DF*4, stream);
  hipMemsetAsync(gcnt, 0, (size_t)NG*4, stream);

  const int NBK = (N+511)>>9;
  k_bhist<<<256,256,0,stream>>>(dst,gb,E);
  k_bscan<<<1,256,0,stream>>>(gb,bbase,bcur,E);
  k_bplace<<<256,256,0,stream>>>(src,dst,bcur,pairs,E);
  k_bcsr<<<NBK,256,0,stream>>>(pairs,bbase,offs,csr,N,E);
  k_prepw<<<256,256,0,stream>>>(ws0,wn0,ws1,wn1,wtb);

  k_embed<<<(N*(DF/8)+255)/256,256,0,stream>>>(feat,emb,(unsigned*)hA,N);
  k_sage<<<(N+31)/32,256,0,stream>>>(hA,offs,csr,wtb,          b0,hB,N);
  k_sage<<<(N+31)/32,256,0,stream>>>(hB,offs,csr,wtb+DF*256,   b1,hA,N);

  k_pool<<<(N+255)/256,128,0,stream>>>(hA,gid,gsum,gcnt,N);
  k_head<<<NG,HID,0,stream>>>(gsum,gcnt,e1w,e1b,e2w,e2b,e3w,e3b,e4w,e4b,
                              pw,pb,out,hidden);
}

// Round 6
// 296.384 us; speedup vs baseline: 5.7047x; 1.1624x over previous
//
#include <hip/hip_runtime.h>
#include <hip/hip_bf16.h>
#include <math.h>

#define DF 128
#define HID 256
#define NG 256

typedef __attribute__((ext_vector_type(8))) short s8v;    // 8 bf16 (4 VGPR)
typedef __attribute__((ext_vector_type(4))) float f32x4;  // MFMA acc
typedef __attribute__((ext_vector_type(2))) float f32x2;

__device__ __forceinline__ unsigned pack2bf(float lo, float hi){
  unsigned a = __bfloat16_as_ushort(__float2bfloat16(lo));
  unsigned b = __bfloat16_as_ushort(__float2bfloat16(hi));
  return a | (b<<16);
}

// =============== binned CSR build ===============
__global__ void k_bhist(const int* __restrict__ dst, int* __restrict__ gb, int E){
  __shared__ int hist[256];
  int t = threadIdx.x;
  hist[t]=0; __syncthreads();
  for (int i = blockIdx.x*256+t; i < E; i += gridDim.x*256)
    atomicAdd(&hist[dst[i]>>9], 1);
  __syncthreads();
  if (hist[t]) atomicAdd(&gb[t], hist[t]);
}

__global__ void k_bscan(const int* __restrict__ gb, int* __restrict__ bbase,
                        int* __restrict__ bcur, int E){
  __shared__ int sh[256];
  int t = threadIdx.x;
  int v = gb[t];
  sh[t]=v; __syncthreads();
  for (int o=1;o<256;o<<=1){
    int x = (t>=o)? sh[t-o] : 0;
    __syncthreads();
    sh[t]+=x;
    __syncthreads();
  }
  int ex = sh[t]-v;
  bbase[t]=ex; bcur[t]=ex;
  if (t==255) bbase[256]=E;
}

__global__ __launch_bounds__(256)
void k_bplace(const int* __restrict__ src, const int* __restrict__ dst,
              int* __restrict__ bcur, uint2* __restrict__ pairs, int E){
  __shared__ int hist[256];
  __shared__ int base[256];
  __shared__ int cur[256];
  const int t = threadIdx.x;
  const int CH = (E + gridDim.x - 1)/gridDim.x;
  const int s = blockIdx.x*CH;
  int e = s+CH; if (e>E) e=E;
  if (s>=E) return;
  hist[t]=0; __syncthreads();
  for (int i=s+t; i<e; i+=256) atomicAdd(&hist[dst[i]>>9],1);
  __syncthreads();
  if (hist[t]){ base[t]=atomicAdd(&bcur[t],hist[t]); }
  cur[t]=0;
  __syncthreads();
  for (int i=s+t; i<e; i+=256){
    int d = dst[i];
    int bk = d>>9;
    int r = atomicAdd(&cur[bk],1);
    pairs[base[bk]+r] = make_uint2((unsigned)src[i],(unsigned)d);
  }
}

__global__ __launch_bounds__(256)
void k_bcsr(const uint2* __restrict__ pairs, const int* __restrict__ bbase,
            int* __restrict__ offs, int* __restrict__ csr, int N, int E){
  __shared__ int ncnt[512];
  __shared__ int noff[512];
  __shared__ int sh[256];
  const int t = threadIdx.x;
  const int b = blockIdx.x;
  const int nb0 = b<<9;
  const int s = bbase[b], e = bbase[b+1];
  ncnt[t]=0; ncnt[t+256]=0;
  __syncthreads();
  for (int i=s+t; i<e; i+=256) atomicAdd(&ncnt[(int)pairs[i].y - nb0], 1);
  __syncthreads();
  int v0 = ncnt[2*t], v1 = ncnt[2*t+1];
  int v = v0+v1;
  sh[t]=v; __syncthreads();
  for (int o=1;o<256;o<<=1){
    int x=(t>=o)?sh[t-o]:0;
    __syncthreads();
    sh[t]+=x;
    __syncthreads();
  }
  int ex = sh[t]-v;
  noff[2*t]=ex; noff[2*t+1]=ex+v0;
  __syncthreads();
  {
    int n0 = nb0 + t;
    if (n0 < N) offs[n0] = s + noff[t];
    int n1 = nb0 + t + 256;
    if (n1 < N) offs[n1] = s + noff[t+256];
    if (b == gridDim.x-1 && t==0) offs[N] = E;
  }
  ncnt[t]=0; ncnt[t+256]=0;
  __syncthreads();
  for (int i=s+t; i<e; i+=256){
    uint2 p = pairs[i];
    int d = (int)p.y - nb0;
    int r = atomicAdd(&ncnt[d],1);
    csr[s + noff[d] + r] = (int)p.x;
  }
}

// ---------------- graph-size histogram (gid sorted -> few distinct per block) ----------------
__global__ void k_gcnt(const int* __restrict__ gid, float* __restrict__ gcnt, int N){
  __shared__ int hist[256];
  int t = threadIdx.x;
  hist[t]=0; __syncthreads();
  for (int i = blockIdx.x*256+t; i < N; i += gridDim.x*256)
    atomicAdd(&hist[gid[i]], 1);
  __syncthreads();
  if (hist[t]) atomicAdd(&gcnt[t], (float)hist[t]);
}

// ---------------- weight prep ----------------
__global__ void k_prepw(const float* __restrict__ ws0, const float* __restrict__ wn0,
                        const float* __restrict__ ws1, const float* __restrict__ wn1,
                        unsigned short* __restrict__ wt){
  int n = blockIdx.x & 127;
  int layer = blockIdx.x >> 7;
  int k = threadIdx.x;                 // 0..255
  const float* ws = layer? ws1 : ws0;
  const float* wn = layer? wn1 : wn0;
  float v = (k<128)? ws[k*DF+n] : wn[(k-128)*DF+n];
  wt[((size_t)layer*DF + n)*256 + k] = __bfloat16_as_ushort(__float2bfloat16(v));
}

// ---------------- embedding gather -> bf16 h + fp8 h ----------------
__global__ void k_embed(const int* __restrict__ feat, const float* __restrict__ emb,
                        unsigned* __restrict__ h_bf, unsigned* __restrict__ h_f8, int N){
  int idx = blockIdx.x*256+threadIdx.x;     // 8-element chunk index
  int total = N*(DF/8);
  if (idx<total){
    int i = idx/(DF/8), c = idx%(DF/8);
    const float4* e4 = (const float4*)emb;
    size_t rb = (size_t)feat[i]*(DF/4);
    float4 v0 = e4[rb + c*2], v1 = e4[rb + c*2+1];
    uint4 o;
    o.x = pack2bf(v0.x,v0.y); o.y = pack2bf(v0.z,v0.w);
    o.z = pack2bf(v1.x,v1.y); o.w = pack2bf(v1.z,v1.w);
    ((uint4*)h_bf)[idx] = o;
    unsigned w0 = __builtin_amdgcn_cvt_pk_fp8_f32(v0.x, v0.y, 0, false);
    w0 = __builtin_amdgcn_cvt_pk_fp8_f32(v0.z, v0.w, w0, true);
    unsigned w1 = __builtin_amdgcn_cvt_pk_fp8_f32(v1.x, v1.y, 0, false);
    w1 = __builtin_amdgcn_cvt_pk_fp8_f32(v1.z, v1.w, w1, true);
    ((uint2*)h_f8)[idx] = make_uint2(w0,w1);
  }
}

// ---------------- fused SAGE layer ----------------
// MODE 0: write h_out (bf16 + fp8).  MODE 1: fused per-graph pool (no h_out).
// gather reads fp8 rows (128B), self path reads bf16; f32 accumulate; MFMA GEMM.
template<int MODE>
__global__ __launch_bounds__(256,6)
void k_sage(const unsigned short* __restrict__ h_in_bf,
            const unsigned char* __restrict__ h_in_f8,
            const int* __restrict__ offs, const int* __restrict__ csr,
            const unsigned short* __restrict__ wt,
            const float* __restrict__ bias,
            unsigned short* __restrict__ h_out_bf,
            unsigned char* __restrict__ h_out_f8,
            const int* __restrict__ gid, float* __restrict__ gsum, int N){
  __shared__ __align__(16) unsigned short s_ab[32*256];   // 16KB
  __shared__ int s_gid[32];
  const int t = threadIdx.x;
  const int node0 = blockIdx.x*32;
  const uint4* hin4 = (const uint4*)h_in_bf;   // 16 uint4 per bf16 row
  const uint4* f8r  = (const uint4*)h_in_f8;   // 8 uint4 per fp8 row

  if (MODE==1 && t<32) s_gid[t] = (node0+t<N)? gid[node0+t] : -1;

  // ---- self rows: bf16 copy into A-tile cols 0..127, swizzled
  for (int idx = t; idx < 512; idx += 256){
    int nn = idx>>4, c = idx&15;
    int node = node0+nn;
    uint4 q = make_uint4(0,0,0,0);
    if (node<N) q = hin4[(size_t)node*16 + c];
    int byte = (nn*512 + c*16) ^ ((nn&7)<<4);
    *(uint4*)((char*)s_ab + byte) = q;
  }

  // ---- neighbor mean from fp8 rows (thread: node t>>3, cols [c*16,c*16+16))
  {
    const int nn = t>>3, c = t&7;
    const int node = node0+nn;
    float a[16];
    #pragma unroll
    for (int j=0;j<16;j++) a[j]=0.f;
    if (node<N){
      int e0=offs[node], e1=offs[node+1];
      int deg = e1-e0;
      if (deg>0){
        #define ACC16(q) { \
          f32x2 u; \
          u=__builtin_amdgcn_cvt_pk_f32_fp8((q).x,false); a[0]+=u[0]; a[1]+=u[1]; \
          u=__builtin_amdgcn_cvt_pk_f32_fp8((q).x,true ); a[2]+=u[0]; a[3]+=u[1]; \
          u=__builtin_amdgcn_cvt_pk_f32_fp8((q).y,false); a[4]+=u[0]; a[5]+=u[1]; \
          u=__builtin_amdgcn_cvt_pk_f32_fp8((q).y,true ); a[6]+=u[0]; a[7]+=u[1]; \
          u=__builtin_amdgcn_cvt_pk_f32_fp8((q).z,false); a[8]+=u[0]; a[9]+=u[1]; \
          u=__builtin_amdgcn_cvt_pk_f32_fp8((q).z,true ); a[10]+=u[0]; a[11]+=u[1]; \
          u=__builtin_amdgcn_cvt_pk_f32_fp8((q).w,false); a[12]+=u[0]; a[13]+=u[1]; \
          u=__builtin_amdgcn_cvt_pk_f32_fp8((q).w,true ); a[14]+=u[0]; a[15]+=u[1]; }
        int e=e0;
        for (; e+4<=e1; e+=4){
          int s0=csr[e], s1=csr[e+1], s2=csr[e+2], s3=csr[e+3];
          uint4 q0 = f8r[(size_t)s0*8 + c];
          uint4 q1 = f8r[(size_t)s1*8 + c];
          uint4 q2 = f8r[(size_t)s2*8 + c];
          uint4 q3 = f8r[(size_t)s3*8 + c];
          ACC16(q0); ACC16(q1); ACC16(q2); ACC16(q3);
        }
        for (; e<e1; ++e){
          uint4 q0 = f8r[(size_t)csr[e]*8 + c];
          ACC16(q0);
        }
        #undef ACC16
        float inv = 1.0f/(float)deg;
        #pragma unroll
        for (int j=0;j<16;j++) a[j]*=inv;
      }
    }
    unsigned pk[8];
    #pragma unroll
    for (int j=0;j<8;j++) pk[j] = pack2bf(a[2*j],a[2*j+1]);
    int byte0 = nn*512 + 256 + c*32;
    int sw = (nn&7)<<4;
    *(uint4*)((char*)s_ab + ((byte0   )^sw)) = make_uint4(pk[0],pk[1],pk[2],pk[3]);
    *(uint4*)((char*)s_ab + ((byte0+16)^sw)) = make_uint4(pk[4],pk[5],pk[6],pk[7]);
  }

  const int wv = t>>6;
  const int lr = t&15;
  const int kg = (t&63)>>4;
  __syncthreads();

  // ---- MFMA main loop, B loaded per K-half from global (L2-resident)
  f32x4 acc00={0,0,0,0}, acc01={0,0,0,0}, acc10={0,0,0,0}, acc11={0,0,0,0};
  const s8v* wt8 = (const s8v*)wt;
  #pragma unroll
  for (int kh=0; kh<2; kh++){
    s8v bfrag[2][4];
    #pragma unroll
    for (int ks=0; ks<4; ks++){
      int kb = (kh*4+ks)*4 + kg;
      bfrag[0][ks] = wt8[(size_t)(wv*32     + lr)*32 + kb];
      bfrag[1][ks] = wt8[(size_t)(wv*32 + 16+ lr)*32 + kb];
    }
    #pragma unroll
    for (int ks=0; ks<4; ks++){
      int cb = (kh*4+ks)*64 + kg*16;
      int r0 = lr, r1 = 16+lr;
      s8v a0 = *(const s8v*)((const char*)s_ab + ((r0*512+cb) ^ ((r0&7)<<4)));
      s8v a1 = *(const s8v*)((const char*)s_ab + ((r1*512+cb) ^ ((r1&7)<<4)));
      acc00 = __builtin_amdgcn_mfma_f32_16x16x32_bf16(a0, bfrag[0][ks], acc00, 0,0,0);
      acc01 = __builtin_amdgcn_mfma_f32_16x16x32_bf16(a0, bfrag[1][ks], acc01, 0,0,0);
      acc10 = __builtin_amdgcn_mfma_f32_16x16x32_bf16(a1, bfrag[0][ks], acc10, 0,0,0);
      acc11 = __builtin_amdgcn_mfma_f32_16x16x32_bf16(a1, bfrag[1][ks], acc11, 0,0,0);
    }
  }
  __syncthreads();

  // ---- epilogue: acc -> LDS f32 [32][128]
  float* cbuf = (float*)s_ab;
  #pragma unroll
  for (int r=0;r<4;r++){
    int row0 = kg*4 + r;
    cbuf[(row0   )*DF + wv*32      + lr] = acc00[r];
    cbuf[(row0   )*DF + wv*32 + 16 + lr] = acc01[r];
    cbuf[(row0+16)*DF + wv*32      + lr] = acc10[r];
    cbuf[(row0+16)*DF + wv*32 + 16 + lr] = acc11[r];
  }
  __syncthreads();

  if (MODE==0){
    int row = t>>3, c0 = (t&7)*16;
    int node = node0+row;
    if (node<N){
      float x[16];
      #pragma unroll
      for (int j=0;j<16;j++) x[j] = fmaxf(cbuf[row*DF + c0 + j] + bias[c0+j], 0.f);
      unsigned pk[8];
      #pragma unroll
      for (int j=0;j<8;j++) pk[j] = pack2bf(x[2*j],x[2*j+1]);
      uint4* dstp = (uint4*)&h_out_bf[(size_t)node*DF + c0];
      dstp[0] = make_uint4(pk[0],pk[1],pk[2],pk[3]);
      dstp[1] = make_uint4(pk[4],pk[5],pk[6],pk[7]);
      unsigned f0 = __builtin_amdgcn_cvt_pk_fp8_f32(x[0], x[1], 0, false);
      f0 = __builtin_amdgcn_cvt_pk_fp8_f32(x[2], x[3], f0, true);
      unsigned f1 = __builtin_amdgcn_cvt_pk_fp8_f32(x[4], x[5], 0, false);
      f1 = __builtin_amdgcn_cvt_pk_fp8_f32(x[6], x[7], f1, true);
      unsigned f2 = __builtin_amdgcn_cvt_pk_fp8_f32(x[8], x[9], 0, false);
      f2 = __builtin_amdgcn_cvt_pk_fp8_f32(x[10], x[11], f2, true);
      unsigned f3 = __builtin_amdgcn_cvt_pk_fp8_f32(x[12], x[13], 0, false);
      f3 = __builtin_amdgcn_cvt_pk_fp8_f32(x[14], x[15], f3, true);
      *(uint4*)&h_out_f8[(size_t)node*DF + c0] = make_uint4(f0,f1,f2,f3);
    }
  } else {
    // fused per-graph pool: thread (rh,d) walks its 16 rows, run-length atomics
    int rh = t>>7, d = t&127;
    float run = 0.f; int cur = -1;
    #pragma unroll 1
    for (int r=0;r<16;++r){
      int nn = rh*16+r;
      int node = node0+nn;
      if (node>=N) break;
      int g = s_gid[nn];
      float v = fmaxf(cbuf[nn*DF+d] + bias[d], 0.f);
      if (g!=cur){
        if (cur>=0) atomicAdd(&gsum[cur*DF+d], run);
        run = 0.f; cur = g;
      }
      run += v;
    }
    if (cur>=0) atomicAdd(&gsum[cur*DF+d], run);
  }
}

// ---------------- fused MLP head ----------------
__global__ __launch_bounds__(256)
void k_head(const float* __restrict__ gsum, const float* __restrict__ gcnt,
            const float* __restrict__ e1w, const float* __restrict__ e1b,
            const float* __restrict__ e2w, const float* __restrict__ e2b,
            const float* __restrict__ e3w, const float* __restrict__ e3b,
            const float* __restrict__ e4w, const float* __restrict__ e4b,
            const float* __restrict__ pw,  const float* __restrict__ pb,
            float* __restrict__ out, float* __restrict__ hidden){
  __shared__ float hg[DF];
  __shared__ float bufA[HID];
  __shared__ float bufB[HID];
  __shared__ float r0[HID], r1[HID];
  const int g = blockIdx.x, t = threadIdx.x;
  if (t<DF) hg[t] = gsum[g*DF+t] / fmaxf(gcnt[g],1.0f);
  __syncthreads();

  float acc = e1b[t];
  for (int k=0;k<DF;++k) acc += hg[k]*e1w[k*HID+t];
  float h1 = fmaxf(acc,0.f);
  hidden[g*HID+t] = h1;
  bufA[t] = h1;
  __syncthreads();

  acc = e2b[t];
  for (int k=0;k<HID;++k) acc += bufA[k]*e2w[k*HID+t];
  bufB[t] = fmaxf(acc,0.f);
  __syncthreads();

  acc = e3b[t];
  for (int k=0;k<HID;++k) acc += bufB[k]*e3w[k*HID+t];
  bufA[t] = fmaxf(acc,0.f);
  __syncthreads();

  acc = e4b[t];
  for (int k=0;k<HID;++k) acc += bufA[k]*e4w[k*HID+t];
  float h4 = fmaxf(acc,0.f);

  r0[t] = h4*pw[t*2+0];
  r1[t] = h4*pw[t*2+1];
  __syncthreads();
  for (int o=128;o>0;o>>=1){
    if (t<o){ r0[t]+=r0[t+o]; r1[t]+=r1[t+o]; }
    __syncthreads();
  }
  if (t==0){
    float y0 = r0[0]+pb[0], y1 = r1[0]+pb[1];
    float m = fmaxf(y0,y1);
    float l = m + logf(expf(y0-m)+expf(y1-m));
    out[g*2+0]=y0-l;
    out[g*2+1]=y1-l;
  }
}

extern "C" void kernel_launch(void* const* d_in, const int* in_sizes, int n_in,
                              void* d_out, int out_size, void* d_ws, size_t ws_size,
                              hipStream_t stream){
  const int* feat = (const int*)d_in[0];
  const int* src  = (const int*)d_in[1];
  const int* dst  = (const int*)d_in[2];
  const int* gid  = (const int*)d_in[3];
  const float* emb = (const float*)d_in[4];
  const float* ws0 = (const float*)d_in[5];
  const float* wn0 = (const float*)d_in[6];
  const float* b0  = (const float*)d_in[7];
  const float* ws1 = (const float*)d_in[8];
  const float* wn1 = (const float*)d_in[9];
  const float* b1  = (const float*)d_in[10];
  const float* e1w = (const float*)d_in[11];
  const float* e1b = (const float*)d_in[12];
  const float* e2w = (const float*)d_in[13];
  const float* e2b = (const float*)d_in[14];
  const float* e3w = (const float*)d_in[15];
  const float* e3b = (const float*)d_in[16];
  const float* e4w = (const float*)d_in[17];
  const float* e4b = (const float*)d_in[18];
  const float* pw  = (const float*)d_in[19];
  const float* pb  = (const float*)d_in[20];
  const int N = in_sizes[0];
  const int E = in_sizes[1];

  char* basep = (char*)d_ws;
  size_t off=0;
  auto alloc=[&](size_t bytes)->void*{
    void* p = basep+off; off=(off+bytes+255)&~(size_t)255; return p;
  };
  unsigned short* hA_bf = (unsigned short*)alloc((size_t)N*DF*2);
  unsigned char*  hA_f8 = (unsigned char*) alloc((size_t)N*DF);
  unsigned short* hB_bf = (unsigned short*)alloc((size_t)N*DF*2);
  unsigned char*  hB_f8 = (unsigned char*) alloc((size_t)N*DF);
  int*   offs  = (int*)  alloc((size_t)(N+1)*4);
  int*   csr   = (int*)  alloc((size_t)E*4);
  int*   gb    = (int*)  alloc(1024);
  int*   bbase = (int*)  alloc(1056);   // 257 ints
  int*   bcur  = (int*)  alloc(1024);
  unsigned short* wtb = (unsigned short*)alloc((size_t)2*DF*256*2);
  float* gsum  = (float*)alloc((size_t)NG*DF*4);
  float* gcnt  = (float*)alloc((size_t)NG*4);
  // pairs aliases hB_bf: consumed by k_bcsr strictly before layer-1 writes hB
  uint2* pairs = (uint2*)hB_bf;
  float* out    = (float*)d_out;
  float* hidden = out + NG*2;

  hipMemsetAsync(gb, 0, 1024, stream);
  hipMemsetAsync(gsum, 0, (size_t)NG*DF*4, stream);
  hipMemsetAsync(gcnt, 0, (size_t)NG*4, stream);

  const int NBK = (N+511)>>9;
  k_bhist<<<256,256,0,stream>>>(dst,gb,E);
  k_bscan<<<1,256,0,stream>>>(gb,bbase,bcur,E);
  k_bplace<<<256,256,0,stream>>>(src,dst,bcur,pairs,E);
  k_bcsr<<<NBK,256,0,stream>>>(pairs,bbase,offs,csr,N,E);
  k_prepw<<<256,256,0,stream>>>(ws0,wn0,ws1,wn1,wtb);
  k_gcnt<<<256,256,0,stream>>>(gid,gcnt,N);

  k_embed<<<(N*(DF/8)+255)/256,256,0,stream>>>(feat,emb,(unsigned*)hA_bf,(unsigned*)hA_f8,N);
  k_sage<0><<<(N+31)/32,256,0,stream>>>(hA_bf,hA_f8,offs,csr,wtb,        b0,
                                        hB_bf,hB_f8,gid,gsum,N);
  k_sage<1><<<(N+31)/32,256,0,stream>>>(hB_bf,hB_f8,offs,csr,wtb+DF*256, b1,
                                        nullptr,nullptr,gid,gsum,N);

  k_head<<<NG,HID,0,stream>>>(gsum,gcnt,e1w,e1b,e2w,e2b,e3w,e3b,e4w,e4b,
                              pw,pb,out,hidden);
}